// Round 4
// baseline (1444.224 us; speedup 1.0000x reference)
//
#include <hip/hip_runtime.h>
#include <hip/hip_bf16.h>
#include <math.h>
#include <string.h>

#define DEV __device__ __forceinline__

typedef __bf16 bf16;
typedef bf16 bf16x8 __attribute__((ext_vector_type(8)));
typedef bf16 bf16x2 __attribute__((ext_vector_type(2)));
typedef float f32x4 __attribute__((ext_vector_type(4)));
typedef unsigned int uint;

constexpr int N_NODES = 50000;
constexpr int N_EDGES = 800000;
constexpr int H = 128;
constexpr int NB_SCAN = (N_NODES + 255) / 256;  // 196

DEV float fsilu(float x) { return x / (1.f + __expf(-x)); }
DEV float fsigmoid(float x) { return 1.f / (1.f + __expf(-x)); }

// ---------------- small prep kernels ----------------

__global__ void transpose_pad_kernel(bf16* __restrict__ dst, const float* __restrict__ src,
                                     int K, int Nf, int KP) {
    int idx = blockIdx.x * 256 + threadIdx.x;
    if (idx >= Nf * KP) return;
    int n = idx / KP, k = idx - n * KP;
    dst[idx] = (k < K) ? (bf16)src[k * Nf + n] : (bf16)0.f;
}

__global__ void h_init_kernel(const float* __restrict__ h, float* __restrict__ h_cur,
                              bf16* __restrict__ h_bf, int n) {
    int i = blockIdx.x * 256 + threadIdx.x;
    if (i < n) { float v = h[i]; h_cur[i] = v; h_bf[i] = (bf16)v; }
}

__global__ void ea_kernel(const float* __restrict__ x, const int* __restrict__ ei,
                          const float* __restrict__ eattr, bf16* __restrict__ ea_bf) {
    int e = blockIdx.x * 256 + threadIdx.x;
    if (e >= N_EDGES) return;
    int r = ei[e], c = ei[N_EDGES + e];
    float dx = x[r * 3 + 0] - x[c * 3 + 0];
    float dy = x[r * 3 + 1] - x[c * 3 + 1];
    float dz = x[r * 3 + 2] - x[c * 3 + 2];
    float radial = dx * dx + dy * dy + dz * dz;
    ea_bf[e * 2 + 0] = (bf16)radial;
    ea_bf[e * 2 + 1] = (bf16)eattr[e];
}

__global__ void out_h_kernel(const float* __restrict__ h_cur, const float* __restrict__ nmask,
                             float* __restrict__ out) {
    int i = blockIdx.x * 256 + threadIdx.x;
    if (i < N_NODES * H) out[i] = h_cur[i] * nmask[i >> 7];
}

// ---------------- CSR build (group edges by row) ----------------

__global__ void count_kernel(const int* __restrict__ ei, int* __restrict__ deg) {
    int e = blockIdx.x * 256 + threadIdx.x;
    if (e < N_EDGES) atomicAdd(&deg[ei[e]], 1);
}

__global__ void scan1_kernel(const int* __restrict__ deg, int* __restrict__ off,
                             int* __restrict__ bsum) {
    __shared__ int s[256];
    int t = threadIdx.x, i = blockIdx.x * 256 + t;
    int v = (i < N_NODES) ? deg[i] : 0;
    s[t] = v;
    __syncthreads();
#pragma unroll
    for (int st = 1; st < 256; st <<= 1) {
        int x = (t >= st) ? s[t - st] : 0;
        __syncthreads();
        s[t] += x;
        __syncthreads();
    }
    if (i < N_NODES) off[i] = s[t] - v;
    if (t == 255) bsum[blockIdx.x] = s[255];
}

__global__ void scan2_kernel(int* __restrict__ bsum) {
    __shared__ int s[256];
    int t = threadIdx.x;
    int v = (t < NB_SCAN) ? bsum[t] : 0;
    s[t] = v;
    __syncthreads();
#pragma unroll
    for (int st = 1; st < 256; st <<= 1) {
        int x = (t >= st) ? s[t - st] : 0;
        __syncthreads();
        s[t] += x;
        __syncthreads();
    }
    if (t < NB_SCAN) bsum[t] = s[t] - v;
}

__global__ void scan3_kernel(int* __restrict__ off, int* __restrict__ cursor,
                             const int* __restrict__ bsum) {
    int i = blockIdx.x * 256 + threadIdx.x;
    if (i >= N_NODES) return;
    int o = off[i] + bsum[blockIdx.x];
    off[i] = o;
    cursor[i] = o;
}

__global__ void fill_kernel(const int* __restrict__ ei, int* __restrict__ cursor,
                            int* __restrict__ eids) {
    int e = blockIdx.x * 256 + threadIdx.x;
    if (e >= N_EDGES) return;
    int slot = atomicAdd(&cursor[ei[e]], 1);
    eids[slot] = e;
}

// ---------------- gathers ----------------

__global__ __launch_bounds__(256) void gather_h_kernel(
    const bf16* __restrict__ ef, const int* __restrict__ off, const int* __restrict__ deg,
    const int* __restrict__ eids, bf16* __restrict__ agg_bf) {
    int t = threadIdx.x, lane = t & 63, wv = t >> 6;
    int n = blockIdx.x * 4 + wv;
    if (n >= N_NODES) return;
    int st = off[n], dg = deg[n];
    float s0 = 0.f, s1 = 0.f;
    for (int k = 0; k < dg; ++k) {
        int e = eids[st + k];
        uint v = *(const uint*)(ef + (size_t)e * H + lane * 2);
        s0 += __uint_as_float(v << 16);
        s1 += __uint_as_float(v & 0xffff0000u);
    }
    bf16x2 o;
    o[0] = (bf16)(s0 * 0.01f);
    o[1] = (bf16)(s1 * 0.01f);
    *(bf16x2*)(agg_bf + (size_t)n * H + lane * 2) = o;
}

__global__ __launch_bounds__(256) void gather_x_kernel(
    const float* __restrict__ trans, const int* __restrict__ off, const int* __restrict__ deg,
    const int* __restrict__ eids, const float* __restrict__ x, const float* __restrict__ nmask,
    float* __restrict__ outx) {
    int t = threadIdx.x, lane = t & 63, wv = t >> 6;
    int n = blockIdx.x * 4 + wv;
    if (n >= N_NODES) return;
    int st = off[n], dg = deg[n];
    float sx = 0.f, sy = 0.f, sz = 0.f;
    for (int k = lane; k < dg; k += 64) {
        int e = eids[st + k];
        sx += trans[e * 3 + 0];
        sy += trans[e * 3 + 1];
        sz += trans[e * 3 + 2];
    }
#pragma unroll
    for (int m = 1; m < 64; m <<= 1) {
        sx += __shfl_xor(sx, m);
        sy += __shfl_xor(sy, m);
        sz += __shfl_xor(sz, m);
    }
    if (lane == 0) {
        float nm = nmask[n];
        outx[n * 3 + 0] = (x[n * 3 + 0] + sx * 0.01f) * nm;
        outx[n * 3 + 1] = (x[n * 3 + 1] + sy * 0.01f) * nm;
        outx[n * 3 + 2] = (x[n * 3 + 2] + sz * 0.01f) * nm;
    }
}

// ---------------- MFMA helpers ----------------
// A layout (16x16x32 bf16): lane holds A[lane&15][(lane>>4)*8 + i]
// C/D layout (HW-verified): col = lane&15, row = (lane>>4)*4 + reg

template <int KCHUNKS, int ASTRIDE, int BSTRIDE>
DEV void wave_gemm(const bf16* A_lds, const bf16* __restrict__ Bt,
                   f32x4 (&acc)[4][2], int lr, int lg, int wv) {
#pragma unroll
    for (int kk = 0; kk < KCHUNKS; ++kk) {
        int ko = kk * 32 + lg * 8;
        bf16x8 a[4], b[2];
#pragma unroll
        for (int er = 0; er < 4; ++er)
            a[er] = *(const bf16x8*)(A_lds + (er * 16 + lr) * ASTRIDE + ko);
#pragma unroll
        for (int j = 0; j < 2; ++j)
            b[j] = *(const bf16x8*)(Bt + (size_t)((wv * 2 + j) * 16 + lr) * BSTRIDE + ko);
#pragma unroll
        for (int er = 0; er < 4; ++er)
#pragma unroll
            for (int j = 0; j < 2; ++j)
                acc[er][j] = __builtin_amdgcn_mfma_f32_16x16x32_bf16(a[er], b[j], acc[er][j], 0, 0, 0);
    }
}

DEV void epi_silu_store(const f32x4 (&acc)[4][2], const float* __restrict__ bias,
                        bf16* out_lds, int OSTRIDE, int lr, int lg, int wv) {
    float b0 = bias[(wv * 2 + 0) * 16 + lr];
    float b1 = bias[(wv * 2 + 1) * 16 + lr];
#pragma unroll
    for (int er = 0; er < 4; ++er) {
#pragma unroll
        for (int j = 0; j < 2; ++j) {
            float bb = j ? b1 : b0;
            int fcol = (wv * 2 + j) * 16 + lr;
#pragma unroll
            for (int r = 0; r < 4; ++r) {
                int rrow = er * 16 + lg * 4 + r;
                out_lds[rrow * OSTRIDE + fcol] = (bf16)fsilu(acc[er][j][r] + bb);
            }
        }
    }
}

// ---------------- edge / coord kernel ----------------
// GEMM1 A-fragments come straight from global (h_bf is L2/L3-resident): no einp LDS,
// no staging pass. LDS = t1 only (~18 KB) -> ~4 blocks/CU at 128 VGPR.
// MODE 0: GCL edge MLP + attention -> ef[e][128] bf16
// MODE 1: coord MLP -> phi -> trans[e][3] f32
template <int MODE>
__global__ __launch_bounds__(256, 4) void edge_kernel(
    const bf16* __restrict__ h_bf, const bf16* __restrict__ ea_bf,
    const int* __restrict__ ei, const float* __restrict__ emask,
    const bf16* __restrict__ w1t, const float* __restrict__ b1,
    const bf16* __restrict__ w2t, const float* __restrict__ b2,
    const float* __restrict__ avec, const float* __restrict__ abias,
    const float* __restrict__ xg, bf16* __restrict__ efout, float* __restrict__ trans) {
    constexpr int TR = 136;
    __shared__ __align__(16) bf16 t1[64 * TR];   // silu(GEMM1) then reused as mij
    __shared__ int row_l[64];
    __shared__ int col_l[64];
    __shared__ float em_l[64];

    int t = threadIdx.x, lane = t & 63, wv = t >> 6;
    int lr = lane & 15, lg = lane >> 4;
    int ebase = blockIdx.x * 64;

    if (t < 64) {
        int e = ebase + t;
        row_l[t] = ei[e];
        col_l[t] = ei[N_EDGES + e];
        em_l[t] = emask[e];
    }
    __syncthreads();

    // per-er A-operand base pointers (per-lane global gather)
    const bf16* arp[4];
    const bf16* acp[4];
    uint eau[4];
#pragma unroll
    for (int er = 0; er < 4; ++er) {
        int el = er * 16 + lr;
        arp[er] = h_bf + (size_t)row_l[el] * H + lg * 8;
        acp[er] = h_bf + (size_t)col_l[el] * H + lg * 8;
        eau[er] = *(const uint*)(ea_bf + (size_t)(ebase + el) * 2);
    }

    const bf16* bp0 = w1t + (size_t)((wv * 2 + 0) * 16 + lr) * 288 + lg * 8;
    const bf16* bp1 = w1t + (size_t)((wv * 2 + 1) * 16 + lr) * 288 + lg * 8;

    f32x4 acc[4][2];
#pragma unroll
    for (int er = 0; er < 4; ++er)
#pragma unroll
        for (int j = 0; j < 2; ++j) acc[er][j] = (f32x4)0.f;

    // kk 0..3: h[row] features; kk 4..7: h[col] features
#pragma unroll
    for (int kk = 0; kk < 8; ++kk) {
        bf16x8 a[4], b[2];
        b[0] = *(const bf16x8*)(bp0 + kk * 32);
        b[1] = *(const bf16x8*)(bp1 + kk * 32);
#pragma unroll
        for (int er = 0; er < 4; ++er)
            a[er] = (kk < 4) ? *(const bf16x8*)(arp[er] + kk * 32)
                             : *(const bf16x8*)(acp[er] + (kk - 4) * 32);
#pragma unroll
        for (int er = 0; er < 4; ++er)
#pragma unroll
            for (int j = 0; j < 2; ++j)
                acc[er][j] = __builtin_amdgcn_mfma_f32_16x16x32_bf16(a[er], b[j], acc[er][j], 0, 0, 0);
    }
    {   // kk 8: [radial, edge_attr, 0...] fragment (nonzero only for lg==0)
        bf16x8 a[4], b[2];
        b[0] = *(const bf16x8*)(bp0 + 8 * 32);
        b[1] = *(const bf16x8*)(bp1 + 8 * 32);
#pragma unroll
        for (int er = 0; er < 4; ++er) {
            bf16x8 f = (bf16x8)(bf16)0.f;
            if (lg == 0) {
                bf16x2 ep;
                memcpy(&ep, &eau[er], 4);
                f[0] = ep[0];
                f[1] = ep[1];
            }
            a[er] = f;
        }
#pragma unroll
        for (int er = 0; er < 4; ++er)
#pragma unroll
            for (int j = 0; j < 2; ++j)
                acc[er][j] = __builtin_amdgcn_mfma_f32_16x16x32_bf16(a[er], b[j], acc[er][j], 0, 0, 0);
    }
    epi_silu_store(acc, b1, t1, TR, lr, lg, wv);
    __syncthreads();

    f32x4 acc2[4][2];
#pragma unroll
    for (int er = 0; er < 4; ++er)
#pragma unroll
        for (int j = 0; j < 2; ++j) acc2[er][j] = (f32x4)0.f;
    wave_gemm<4, TR, 128>(t1, w2t, acc2, lr, lg, wv);
    __syncthreads();  // all waves done reading t1 -> safe to overwrite with mij

    bf16* mij = t1;
    epi_silu_store(acc2, b2, mij, TR, lr, lg, wv);
    __syncthreads();

    // per-edge dot over 128 feats: 4 threads/edge, shfl reduce
    int el = t >> 2, q = t & 3;
    const bf16* mrow = mij + el * TR + q * 32;
    float part = 0.f;
#pragma unroll
    for (int c = 0; c < 4; ++c) {
        bf16x8 v = *(const bf16x8*)(mrow + c * 8);
#pragma unroll
        for (int jj = 0; jj < 8; ++jj) part += (float)v[jj] * avec[q * 32 + c * 8 + jj];
    }
    part += __shfl_xor(part, 1);
    part += __shfl_xor(part, 2);

    if (MODE == 0) {
        float att = fsigmoid(part + abias[0]);
        float scale = att * em_l[el];
        bf16* edst = efout + (size_t)(ebase + el) * H + q * 32;
#pragma unroll
        for (int c = 0; c < 4; ++c) {
            bf16x8 v = *(const bf16x8*)(mrow + c * 8);
            bf16x8 o;
#pragma unroll
            for (int jj = 0; jj < 8; ++jj) o[jj] = (bf16)((float)v[jj] * scale);
            *(bf16x8*)(edst + c * 8) = o;
        }
    } else {
        if (q == 0) {
            int rr = row_l[el], cc = col_l[el];
            float dx = xg[rr * 3 + 0] - xg[cc * 3 + 0];
            float dy = xg[rr * 3 + 1] - xg[cc * 3 + 1];
            float dz = xg[rr * 3 + 2] - xg[cc * 3 + 2];
            float radial = dx * dx + dy * dy + dz * dz;
            float inv = 1.f / (sqrtf(radial + 1e-8f) + 1.f);
            float s = part * em_l[el] * inv;
            int e = ebase + el;
            trans[e * 3 + 0] = dx * s;
            trans[e * 3 + 1] = dy * s;
            trans[e * 3 + 2] = dz * s;
        }
    }
}

// ---------------- node MLP kernel ----------------
__global__ __launch_bounds__(256, 2) void node_kernel(
    float* __restrict__ h_cur, bf16* __restrict__ h_bf, const bf16* __restrict__ agg_bf,
    const bf16* __restrict__ w1t, const float* __restrict__ b1,
    const bf16* __restrict__ w2t, const float* __restrict__ b2,
    const float* __restrict__ nmask) {
    constexpr int SRN = 264;
    constexpr int TRN = 136;
    __shared__ __align__(16) bf16 ninp[64 * SRN];
    __shared__ __align__(16) bf16 t1[64 * TRN];

    int t = threadIdx.x, lane = t & 63, wv = t >> 6;
    int lr = lane & 15, lg = lane >> 4;
    int nbase = blockIdx.x * 64;

    {   // stage ninp = [bf16(h), agg_bf]
        int nl = t >> 2, q = t & 3;
        int node = nbase + nl;
        bf16* dst = ninp + nl * SRN;
        if (node < N_NODES) {
            const float4* hr = (const float4*)(h_cur + (size_t)node * H);
            const bf16* ar = agg_bf + (size_t)node * H;
#pragma unroll
            for (int pp = 0; pp < 8; ++pp) {
                int ch = pp * 4 + q;
                float4 v = hr[ch];
                dst[ch * 4 + 0] = (bf16)v.x; dst[ch * 4 + 1] = (bf16)v.y;
                dst[ch * 4 + 2] = (bf16)v.z; dst[ch * 4 + 3] = (bf16)v.w;
            }
#pragma unroll
            for (int pp = 0; pp < 4; ++pp) {
                int ch = pp * 4 + q;
                *(bf16x8*)(dst + 128 + ch * 8) = *(const bf16x8*)(ar + ch * 8);
            }
        } else {
#pragma unroll
            for (int pp = 0; pp < 8; ++pp) {
                int ch = pp * 4 + q;
#pragma unroll
                for (int k = 0; k < 4; ++k) {
                    dst[ch * 4 + k] = (bf16)0.f;
                    dst[128 + ch * 4 + k] = (bf16)0.f;
                }
            }
        }
    }
    __syncthreads();

    f32x4 acc[4][2];
#pragma unroll
    for (int er = 0; er < 4; ++er)
#pragma unroll
        for (int j = 0; j < 2; ++j) acc[er][j] = (f32x4)0.f;
    wave_gemm<8, SRN, 256>(ninp, w1t, acc, lr, lg, wv);
    epi_silu_store(acc, b1, t1, TRN, lr, lg, wv);
    __syncthreads();

    f32x4 acc2[4][2];
#pragma unroll
    for (int er = 0; er < 4; ++er)
#pragma unroll
        for (int j = 0; j < 2; ++j) acc2[er][j] = (f32x4)0.f;
    wave_gemm<4, TRN, 128>(t1, w2t, acc2, lr, lg, wv);

    float bb0 = b2[(wv * 2 + 0) * 16 + lr];
    float bb1 = b2[(wv * 2 + 1) * 16 + lr];
#pragma unroll
    for (int er = 0; er < 4; ++er) {
#pragma unroll
        for (int j = 0; j < 2; ++j) {
            float bb = j ? bb1 : bb0;
            int feat = (wv * 2 + j) * 16 + lr;
#pragma unroll
            for (int r = 0; r < 4; ++r) {
                int node = nbase + er * 16 + lg * 4 + r;
                if (node < N_NODES) {
                    size_t idx = (size_t)node * H + feat;
                    float nm = nmask[node];
                    float v = (h_cur[idx] + acc2[er][j][r] + bb) * nm;  // fp32 residual
                    h_cur[idx] = v;
                    h_bf[idx] = (bf16)v;
                }
            }
        }
    }
}

// ---------------- launch ----------------
extern "C" void kernel_launch(void* const* d_in, const int* in_sizes, int n_in,
                              void* d_out, int out_size, void* d_ws, size_t ws_size,
                              hipStream_t stream) {
    (void)in_sizes; (void)n_in; (void)out_size; (void)ws_size;
    const float* h_in  = (const float*)d_in[0];
    const float* x_in  = (const float*)d_in[1];
    const int*   ei    = (const int*)d_in[2];
    const float* eattr = (const float*)d_in[3];
    const float* nmask = (const float*)d_in[4];
    const float* emask = (const float*)d_in[5];
    const float* e_w1  = (const float*)d_in[6];
    const float* e_b1  = (const float*)d_in[7];
    const float* e_w2  = (const float*)d_in[8];
    const float* e_b2  = (const float*)d_in[9];
    const float* a_w   = (const float*)d_in[10];
    const float* a_b   = (const float*)d_in[11];
    const float* n_w1  = (const float*)d_in[12];
    const float* n_b1  = (const float*)d_in[13];
    const float* n_w2  = (const float*)d_in[14];
    const float* n_b2  = (const float*)d_in[15];
    const float* c_w1  = (const float*)d_in[16];
    const float* c_b1  = (const float*)d_in[17];
    const float* c_w2  = (const float*)d_in[18];
    const float* c_b2  = (const float*)d_in[19];
    const float* c_w3  = (const float*)d_in[20];
    float* out = (float*)d_out;

    char* p = (char*)d_ws;
    auto alloc = [&](size_t bytes) { char* r = p; p += (bytes + 255) & ~(size_t)255; return r; };
    float* h_cur  = (float*)alloc((size_t)N_NODES * H * 4);
    bf16*  h_bf   = (bf16*) alloc((size_t)N_NODES * H * 2);
    bf16*  agg_bf = (bf16*) alloc((size_t)N_NODES * H * 2);
    bf16*  ea_bf  = (bf16*) alloc((size_t)N_EDGES * 2 * 2);
    bf16*  ef     = (bf16*) alloc((size_t)N_EDGES * H * 2);   // 204.8 MB
    float* trans  = (float*)ef;                               // alias: ef dead before edge<1>
    int*   deg    = (int*)  alloc((size_t)N_NODES * 4);
    int*   off    = (int*)  alloc((size_t)N_NODES * 4);
    int*   cursor = (int*)  alloc((size_t)N_NODES * 4);
    int*   bsum   = (int*)  alloc((size_t)NB_SCAN * 4);
    int*   eids   = (int*)  alloc((size_t)N_EDGES * 4);
    bf16*  e_w1t  = (bf16*) alloc((size_t)2 * 128 * 288 * 2);
    bf16*  e_w2t  = (bf16*) alloc((size_t)2 * 128 * 128 * 2);
    bf16*  n_w1t  = (bf16*) alloc((size_t)2 * 128 * 256 * 2);
    bf16*  n_w2t  = (bf16*) alloc((size_t)2 * 128 * 128 * 2);
    bf16*  c_w1t  = (bf16*) alloc((size_t)128 * 288 * 2);
    bf16*  c_w2t  = (bf16*) alloc((size_t)128 * 128 * 2);

    auto tp = [&](bf16* dst, const float* src, int K, int KP) {
        int tot = 128 * KP;
        transpose_pad_kernel<<<(tot + 255) / 256, 256, 0, stream>>>(dst, src, K, 128, KP);
    };
    tp(e_w1t, e_w1, 258, 288);               tp(e_w1t + 128 * 288, e_w1 + 258 * 128, 258, 288);
    tp(e_w2t, e_w2, 128, 128);               tp(e_w2t + 128 * 128, e_w2 + 128 * 128, 128, 128);
    tp(n_w1t, n_w1, 256, 256);               tp(n_w1t + 128 * 256, n_w1 + 256 * 128, 256, 256);
    tp(n_w2t, n_w2, 128, 128);               tp(n_w2t + 128 * 128, n_w2 + 128 * 128, 128, 128);
    tp(c_w1t, c_w1, 258, 288);
    tp(c_w2t, c_w2, 128, 128);

    h_init_kernel<<<(N_NODES * H + 255) / 256, 256, 0, stream>>>(h_in, h_cur, h_bf, N_NODES * H);
    ea_kernel<<<(N_EDGES + 255) / 256, 256, 0, stream>>>(x_in, ei, eattr, ea_bf);

    // ---- CSR build ----
    hipMemsetAsync(deg, 0, (size_t)N_NODES * 4, stream);
    count_kernel<<<(N_EDGES + 255) / 256, 256, 0, stream>>>(ei, deg);
    scan1_kernel<<<NB_SCAN, 256, 0, stream>>>(deg, off, bsum);
    scan2_kernel<<<1, 256, 0, stream>>>(bsum);
    scan3_kernel<<<NB_SCAN, 256, 0, stream>>>(off, cursor, bsum);
    fill_kernel<<<(N_EDGES + 255) / 256, 256, 0, stream>>>(ei, cursor, eids);

    int ngrid = (N_NODES + 3) / 4;
    for (int i = 0; i < 2; ++i) {
        edge_kernel<0><<<N_EDGES / 64, 256, 0, stream>>>(
            h_bf, ea_bf, ei, emask,
            e_w1t + (size_t)i * 128 * 288, e_b1 + i * H,
            e_w2t + (size_t)i * 128 * 128, e_b2 + i * H,
            a_w + i * H, a_b + i, nullptr, ef, nullptr);
        gather_h_kernel<<<ngrid, 256, 0, stream>>>(ef, off, deg, eids, agg_bf);
        node_kernel<<<(N_NODES + 63) / 64, 256, 0, stream>>>(
            h_cur, h_bf, agg_bf,
            n_w1t + (size_t)i * 128 * 256, n_b1 + i * H,
            n_w2t + (size_t)i * 128 * 128, n_b2 + i * H, nmask);
    }
    edge_kernel<1><<<N_EDGES / 64, 256, 0, stream>>>(
        h_bf, ea_bf, ei, emask,
        c_w1t, c_b1, c_w2t, c_b2, c_w3, nullptr, x_in, nullptr, trans);
    gather_x_kernel<<<ngrid, 256, 0, stream>>>(trans, off, deg, eids, x_in, nmask,
                                               out + (size_t)N_NODES * H);

    out_h_kernel<<<(N_NODES * H + 255) / 256, 256, 0, stream>>>(h_cur, nmask, out);
}

// Round 5
// 1135.278 us; speedup vs baseline: 1.2721x; 1.2721x over previous
//
#include <hip/hip_runtime.h>
#include <hip/hip_bf16.h>
#include <math.h>
#include <string.h>

#define DEV __device__ __forceinline__

typedef __bf16 bf16;
typedef bf16 bf16x8 __attribute__((ext_vector_type(8)));
typedef bf16 bf16x2 __attribute__((ext_vector_type(2)));
typedef float f32x4 __attribute__((ext_vector_type(4)));
typedef unsigned int uint;

constexpr int N_NODES = 50000;
constexpr int N_EDGES = 800000;
constexpr int H = 128;
constexpr int NB_SCAN = (N_NODES + 255) / 256;  // 196

DEV float fsilu(float x) { return x / (1.f + __expf(-x)); }
DEV float fsigmoid(float x) { return 1.f / (1.f + __expf(-x)); }

// ---------------- small prep kernels ----------------

__global__ void transpose_pad_kernel(bf16* __restrict__ dst, const float* __restrict__ src,
                                     int K, int Nf, int KP) {
    int idx = blockIdx.x * 256 + threadIdx.x;
    if (idx >= Nf * KP) return;
    int n = idx / KP, k = idx - n * KP;
    dst[idx] = (k < K) ? (bf16)src[k * Nf + n] : (bf16)0.f;
}

__global__ void h_init_kernel(const float* __restrict__ h, float* __restrict__ h_cur,
                              bf16* __restrict__ h_bf, int n) {
    int i = blockIdx.x * 256 + threadIdx.x;
    if (i < n) { float v = h[i]; h_cur[i] = v; h_bf[i] = (bf16)v; }
}

__global__ void ea_kernel(const float* __restrict__ x, const int* __restrict__ ei,
                          const float* __restrict__ eattr, bf16* __restrict__ ea_bf) {
    int e = blockIdx.x * 256 + threadIdx.x;
    if (e >= N_EDGES) return;
    int r = ei[e], c = ei[N_EDGES + e];
    float dx = x[r * 3 + 0] - x[c * 3 + 0];
    float dy = x[r * 3 + 1] - x[c * 3 + 1];
    float dz = x[r * 3 + 2] - x[c * 3 + 2];
    float radial = dx * dx + dy * dy + dz * dz;
    ea_bf[e * 2 + 0] = (bf16)radial;
    ea_bf[e * 2 + 1] = (bf16)eattr[e];
}

__global__ void out_h_kernel(const float* __restrict__ h_cur, const float* __restrict__ nmask,
                             float* __restrict__ out) {
    int i = blockIdx.x * 256 + threadIdx.x;
    if (i < N_NODES * H) out[i] = h_cur[i] * nmask[i >> 7];
}

// ---------------- CSR build (group edges by row) ----------------

__global__ void count_kernel(const int* __restrict__ ei, int* __restrict__ deg) {
    int e = blockIdx.x * 256 + threadIdx.x;
    if (e < N_EDGES) atomicAdd(&deg[ei[e]], 1);
}

__global__ void scan1_kernel(const int* __restrict__ deg, int* __restrict__ off,
                             int* __restrict__ bsum) {
    __shared__ int s[256];
    int t = threadIdx.x, i = blockIdx.x * 256 + t;
    int v = (i < N_NODES) ? deg[i] : 0;
    s[t] = v;
    __syncthreads();
#pragma unroll
    for (int st = 1; st < 256; st <<= 1) {
        int x = (t >= st) ? s[t - st] : 0;
        __syncthreads();
        s[t] += x;
        __syncthreads();
    }
    if (i < N_NODES) off[i] = s[t] - v;
    if (t == 255) bsum[blockIdx.x] = s[255];
}

__global__ void scan2_kernel(int* __restrict__ bsum) {
    __shared__ int s[256];
    int t = threadIdx.x;
    int v = (t < NB_SCAN) ? bsum[t] : 0;
    s[t] = v;
    __syncthreads();
#pragma unroll
    for (int st = 1; st < 256; st <<= 1) {
        int x = (t >= st) ? s[t - st] : 0;
        __syncthreads();
        s[t] += x;
        __syncthreads();
    }
    if (t < NB_SCAN) bsum[t] = s[t] - v;
}

__global__ void scan3_kernel(int* __restrict__ off, int* __restrict__ cursor,
                             const int* __restrict__ bsum) {
    int i = blockIdx.x * 256 + threadIdx.x;
    if (i >= N_NODES) return;
    int o = off[i] + bsum[blockIdx.x];
    off[i] = o;
    cursor[i] = o;
}

__global__ void fill_kernel(const int* __restrict__ ei, int* __restrict__ cursor,
                            int* __restrict__ eids) {
    int e = blockIdx.x * 256 + threadIdx.x;
    if (e >= N_EDGES) return;
    int slot = atomicAdd(&cursor[ei[e]], 1);
    eids[slot] = e;
}

// ---------------- gathers ----------------

__global__ __launch_bounds__(256) void gather_h_kernel(
    const bf16* __restrict__ ef, const int* __restrict__ off, const int* __restrict__ deg,
    const int* __restrict__ eids, bf16* __restrict__ agg_bf) {
    int t = threadIdx.x, lane = t & 63, wv = t >> 6;
    int n = blockIdx.x * 4 + wv;
    if (n >= N_NODES) return;
    int st = off[n], dg = deg[n];
    float s0 = 0.f, s1 = 0.f;
    for (int k = 0; k < dg; ++k) {
        int e = eids[st + k];
        uint v = *(const uint*)(ef + (size_t)e * H + lane * 2);
        s0 += __uint_as_float(v << 16);
        s1 += __uint_as_float(v & 0xffff0000u);
    }
    bf16x2 o;
    o[0] = (bf16)(s0 * 0.01f);
    o[1] = (bf16)(s1 * 0.01f);
    *(bf16x2*)(agg_bf + (size_t)n * H + lane * 2) = o;
}

__global__ __launch_bounds__(256) void gather_x_kernel(
    const float* __restrict__ trans, const int* __restrict__ off, const int* __restrict__ deg,
    const int* __restrict__ eids, const float* __restrict__ x, const float* __restrict__ nmask,
    float* __restrict__ outx) {
    int t = threadIdx.x, lane = t & 63, wv = t >> 6;
    int n = blockIdx.x * 4 + wv;
    if (n >= N_NODES) return;
    int st = off[n], dg = deg[n];
    float sx = 0.f, sy = 0.f, sz = 0.f;
    for (int k = lane; k < dg; k += 64) {
        int e = eids[st + k];
        sx += trans[e * 3 + 0];
        sy += trans[e * 3 + 1];
        sz += trans[e * 3 + 2];
    }
#pragma unroll
    for (int m = 1; m < 64; m <<= 1) {
        sx += __shfl_xor(sx, m);
        sy += __shfl_xor(sy, m);
        sz += __shfl_xor(sz, m);
    }
    if (lane == 0) {
        float nm = nmask[n];
        outx[n * 3 + 0] = (x[n * 3 + 0] + sx * 0.01f) * nm;
        outx[n * 3 + 1] = (x[n * 3 + 1] + sy * 0.01f) * nm;
        outx[n * 3 + 2] = (x[n * 3 + 2] + sz * 0.01f) * nm;
    }
}

// ---------------- MFMA helpers ----------------
// A layout (16x16x32 bf16): lane holds A[lane&15][(lane>>4)*8 + i]
// C/D layout (HW-verified): col = lane&15, row = (lane>>4)*4 + reg

template <int KCHUNKS, int ASTRIDE, int BSTRIDE>
DEV void wave_gemm(const bf16* A_lds, const bf16* __restrict__ Bt,
                   f32x4 (&acc)[4][2], int lr, int lg, int wv) {
#pragma unroll
    for (int kk = 0; kk < KCHUNKS; ++kk) {
        int ko = kk * 32 + lg * 8;
        bf16x8 a[4], b[2];
#pragma unroll
        for (int er = 0; er < 4; ++er)
            a[er] = *(const bf16x8*)(A_lds + (er * 16 + lr) * ASTRIDE + ko);
#pragma unroll
        for (int j = 0; j < 2; ++j)
            b[j] = *(const bf16x8*)(Bt + (size_t)((wv * 2 + j) * 16 + lr) * BSTRIDE + ko);
#pragma unroll
        for (int er = 0; er < 4; ++er)
#pragma unroll
            for (int j = 0; j < 2; ++j)
                acc[er][j] = __builtin_amdgcn_mfma_f32_16x16x32_bf16(a[er], b[j], acc[er][j], 0, 0, 0);
    }
}

DEV void epi_silu_store(const f32x4 (&acc)[4][2], const float* __restrict__ bias,
                        bf16* out_lds, int OSTRIDE, int lr, int lg, int wv) {
    float b0 = bias[(wv * 2 + 0) * 16 + lr];
    float b1 = bias[(wv * 2 + 1) * 16 + lr];
#pragma unroll
    for (int er = 0; er < 4; ++er) {
#pragma unroll
        for (int j = 0; j < 2; ++j) {
            float bb = j ? b1 : b0;
            int fcol = (wv * 2 + j) * 16 + lr;
#pragma unroll
            for (int r = 0; r < 4; ++r) {
                int rrow = er * 16 + lg * 4 + r;
                out_lds[rrow * OSTRIDE + fcol] = (bf16)fsilu(acc[er][j][r] + bb);
            }
        }
    }
}

// swizzled variant: [64][128] with 16B-slot XOR (slot ^= row&7)
DEV void epi_silu_store_swz(const f32x4 (&acc)[4][2], const float* __restrict__ bias,
                            bf16* out_lds, int lr, int lg, int wv) {
    float b0 = bias[(wv * 2 + 0) * 16 + lr];
    float b1 = bias[(wv * 2 + 1) * 16 + lr];
#pragma unroll
    for (int er = 0; er < 4; ++er) {
#pragma unroll
        for (int j = 0; j < 2; ++j) {
            float bb = j ? b1 : b0;
            int fcol = (wv * 2 + j) * 16 + lr;
#pragma unroll
            for (int r = 0; r < 4; ++r) {
                int rrow = er * 16 + lg * 4 + r;
                int sl = (fcol >> 3) ^ (rrow & 7);
                out_lds[rrow * 128 + sl * 8 + (fcol & 7)] = (bf16)fsilu(acc[er][j][r] + bb);
            }
        }
    }
}

// ---------------- edge / coord kernel ----------------
// Staging: async global_load_lds (16B/lane) into AR/AC [64][128] with XOR slot
// swizzle applied on the GLOBAL source (linear LDS dest, rule: both-sides-or-neither).
// ea K-tail handled as a register fragment (kk=8). mij reuses AC (swizzled).
// MODE 0: GCL edge MLP + attention -> ef[e][128] bf16
// MODE 1: coord MLP -> phi -> trans[e][3] f32
template <int MODE>
__global__ __launch_bounds__(256, 3) void edge_kernel(
    const bf16* __restrict__ h_bf, const bf16* __restrict__ ea_bf,
    const int* __restrict__ ei, const float* __restrict__ emask,
    const bf16* __restrict__ w1t, const float* __restrict__ b1,
    const bf16* __restrict__ w2t, const float* __restrict__ b2,
    const float* __restrict__ avec, const float* __restrict__ abias,
    const float* __restrict__ xg, bf16* __restrict__ efout, float* __restrict__ trans) {
    constexpr int TR = 136;
    __shared__ __align__(16) bf16 AR[64 * 128];   // h[row] tile, swizzled
    __shared__ __align__(16) bf16 AC[64 * 128];   // h[col] tile, swizzled; reused as mij
    __shared__ __align__(16) bf16 t1[64 * TR];    // silu(GEMM1) output
    __shared__ int row_l[64];
    __shared__ int col_l[64];
    __shared__ float em_l[64];

    int t = threadIdx.x, lane = t & 63, wv = t >> 6;
    int lr = lane & 15, lg = lane >> 4;
    int ebase = blockIdx.x * 64;

    {   // async stage: each instr writes 4 rows x 256B = 1024B linear LDS
        int rsub = lane >> 4;     // row within 4-row group
        int slot = lane & 15;     // 16B slot within row
#pragma unroll
        for (int u = 0; u < 4; ++u) {
            int r = wv * 16 + u * 4 + rsub;
            int nr = ei[ebase + r];
            int sl = slot ^ (r & 7);   // pre-swizzled source
            const bf16* gp = h_bf + (size_t)nr * H + sl * 8;
            __builtin_amdgcn_global_load_lds(
                (const __attribute__((address_space(1))) void*)gp,
                (__attribute__((address_space(3))) void*)&AR[(wv * 16 + u * 4) * 128],
                16, 0, 0);
        }
#pragma unroll
        for (int u = 0; u < 4; ++u) {
            int r = wv * 16 + u * 4 + rsub;
            int nc = ei[N_EDGES + ebase + r];
            int sl = slot ^ (r & 7);
            const bf16* gp = h_bf + (size_t)nc * H + sl * 8;
            __builtin_amdgcn_global_load_lds(
                (const __attribute__((address_space(1))) void*)gp,
                (__attribute__((address_space(3))) void*)&AC[(wv * 16 + u * 4) * 128],
                16, 0, 0);
        }
    }
    if (t < 64) {
        int e = ebase + t;
        row_l[t] = ei[e];
        col_l[t] = ei[N_EDGES + e];
        em_l[t] = emask[e];
    }

    // ea K-tail in registers
    uint eau[4];
#pragma unroll
    for (int er = 0; er < 4; ++er)
        eau[er] = *(const uint*)(ea_bf + (size_t)(ebase + er * 16 + lr) * 2);

    const bf16* bp0 = w1t + (size_t)((wv * 2 + 0) * 16 + lr) * 288 + lg * 8;
    const bf16* bp1 = w1t + (size_t)((wv * 2 + 1) * 16 + lr) * 288 + lg * 8;

    __syncthreads();  // drains global_load_lds (vmcnt) + meta stores

    f32x4 acc[4][2];
#pragma unroll
    for (int er = 0; er < 4; ++er)
#pragma unroll
        for (int j = 0; j < 2; ++j) acc[er][j] = (f32x4)0.f;

    // kk 0..3: h[row] from AR; kk 4..7: h[col] from AC (swizzled reads)
#pragma unroll
    for (int kk = 0; kk < 8; ++kk) {
        const bf16* Ab = (kk < 4) ? AR : AC;
        int k4 = kk & 3;
        bf16x8 a[4], b[2];
        b[0] = *(const bf16x8*)(bp0 + kk * 32);
        b[1] = *(const bf16x8*)(bp1 + kk * 32);
#pragma unroll
        for (int er = 0; er < 4; ++er) {
            int sl = (k4 * 4 + lg) ^ (lr & 7);
            a[er] = *(const bf16x8*)(Ab + (er * 16 + lr) * 128 + sl * 8);
        }
#pragma unroll
        for (int er = 0; er < 4; ++er)
#pragma unroll
            for (int j = 0; j < 2; ++j)
                acc[er][j] = __builtin_amdgcn_mfma_f32_16x16x32_bf16(a[er], b[j], acc[er][j], 0, 0, 0);
    }
    {   // kk 8: [radial, edge_attr, 0...] fragment (nonzero only for lg==0)
        bf16x8 a[4], b[2];
        b[0] = *(const bf16x8*)(bp0 + 8 * 32);
        b[1] = *(const bf16x8*)(bp1 + 8 * 32);
#pragma unroll
        for (int er = 0; er < 4; ++er) {
            bf16x8 f = (bf16x8)(bf16)0.f;
            if (lg == 0) {
                bf16x2 ep;
                memcpy(&ep, &eau[er], 4);
                f[0] = ep[0];
                f[1] = ep[1];
            }
            a[er] = f;
        }
#pragma unroll
        for (int er = 0; er < 4; ++er)
#pragma unroll
            for (int j = 0; j < 2; ++j)
                acc[er][j] = __builtin_amdgcn_mfma_f32_16x16x32_bf16(a[er], b[j], acc[er][j], 0, 0, 0);
    }
    epi_silu_store(acc, b1, t1, TR, lr, lg, wv);
    __syncthreads();  // t1 ready; all waves done with AR/AC GEMM1 reads

    f32x4 acc2[4][2];
#pragma unroll
    for (int er = 0; er < 4; ++er)
#pragma unroll
        for (int j = 0; j < 2; ++j) acc2[er][j] = (f32x4)0.f;
    wave_gemm<4, TR, 128>(t1, w2t, acc2, lr, lg, wv);

    bf16* mij = AC;  // safe: all GEMM1 AC reads completed before previous barrier
    epi_silu_store_swz(acc2, b2, mij, lr, lg, wv);
    __syncthreads();

    // per-edge dot over 128 feats: 4 threads/edge, shfl reduce (swizzled mij reads)
    int el = t >> 2, q = t & 3;
    float part = 0.f;
    bf16x8 mv[4];
#pragma unroll
    for (int c = 0; c < 4; ++c) {
        int sl = (q * 4 + c) ^ (el & 7);
        mv[c] = *(const bf16x8*)(mij + el * 128 + sl * 8);
#pragma unroll
        for (int jj = 0; jj < 8; ++jj) part += (float)mv[c][jj] * avec[q * 32 + c * 8 + jj];
    }
    part += __shfl_xor(part, 1);
    part += __shfl_xor(part, 2);

    if (MODE == 0) {
        float att = fsigmoid(part + abias[0]);
        float scale = att * em_l[el];
        bf16* edst = efout + (size_t)(ebase + el) * H + q * 32;
#pragma unroll
        for (int c = 0; c < 4; ++c) {
            bf16x8 o;
#pragma unroll
            for (int jj = 0; jj < 8; ++jj) o[jj] = (bf16)((float)mv[c][jj] * scale);
            *(bf16x8*)(edst + c * 8) = o;
        }
    } else {
        if (q == 0) {
            int rr = row_l[el], cc = col_l[el];
            float dx = xg[rr * 3 + 0] - xg[cc * 3 + 0];
            float dy = xg[rr * 3 + 1] - xg[cc * 3 + 1];
            float dz = xg[rr * 3 + 2] - xg[cc * 3 + 2];
            float radial = dx * dx + dy * dy + dz * dz;
            float inv = 1.f / (sqrtf(radial + 1e-8f) + 1.f);
            float s = part * em_l[el] * inv;
            int e = ebase + el;
            trans[e * 3 + 0] = dx * s;
            trans[e * 3 + 1] = dy * s;
            trans[e * 3 + 2] = dz * s;
        }
    }
}

// ---------------- node MLP kernel ----------------
__global__ __launch_bounds__(256, 2) void node_kernel(
    float* __restrict__ h_cur, bf16* __restrict__ h_bf, const bf16* __restrict__ agg_bf,
    const bf16* __restrict__ w1t, const float* __restrict__ b1,
    const bf16* __restrict__ w2t, const float* __restrict__ b2,
    const float* __restrict__ nmask) {
    constexpr int SRN = 264;
    constexpr int TRN = 136;
    __shared__ __align__(16) bf16 ninp[64 * SRN];
    __shared__ __align__(16) bf16 t1[64 * TRN];

    int t = threadIdx.x, lane = t & 63, wv = t >> 6;
    int lr = lane & 15, lg = lane >> 4;
    int nbase = blockIdx.x * 64;

    {   // stage ninp = [bf16(h), agg_bf]
        int nl = t >> 2, q = t & 3;
        int node = nbase + nl;
        bf16* dst = ninp + nl * SRN;
        if (node < N_NODES) {
            const float4* hr = (const float4*)(h_cur + (size_t)node * H);
            const bf16* ar = agg_bf + (size_t)node * H;
#pragma unroll
            for (int pp = 0; pp < 8; ++pp) {
                int ch = pp * 4 + q;
                float4 v = hr[ch];
                dst[ch * 4 + 0] = (bf16)v.x; dst[ch * 4 + 1] = (bf16)v.y;
                dst[ch * 4 + 2] = (bf16)v.z; dst[ch * 4 + 3] = (bf16)v.w;
            }
#pragma unroll
            for (int pp = 0; pp < 4; ++pp) {
                int ch = pp * 4 + q;
                *(bf16x8*)(dst + 128 + ch * 8) = *(const bf16x8*)(ar + ch * 8);
            }
        } else {
#pragma unroll
            for (int pp = 0; pp < 8; ++pp) {
                int ch = pp * 4 + q;
#pragma unroll
                for (int k = 0; k < 4; ++k) {
                    dst[ch * 4 + k] = (bf16)0.f;
                    dst[128 + ch * 4 + k] = (bf16)0.f;
                }
            }
        }
    }
    __syncthreads();

    f32x4 acc[4][2];
#pragma unroll
    for (int er = 0; er < 4; ++er)
#pragma unroll
        for (int j = 0; j < 2; ++j) acc[er][j] = (f32x4)0.f;
    wave_gemm<8, SRN, 256>(ninp, w1t, acc, lr, lg, wv);
    epi_silu_store(acc, b1, t1, TRN, lr, lg, wv);
    __syncthreads();

    f32x4 acc2[4][2];
#pragma unroll
    for (int er = 0; er < 4; ++er)
#pragma unroll
        for (int j = 0; j < 2; ++j) acc2[er][j] = (f32x4)0.f;
    wave_gemm<4, TRN, 128>(t1, w2t, acc2, lr, lg, wv);

    float bb0 = b2[(wv * 2 + 0) * 16 + lr];
    float bb1 = b2[(wv * 2 + 1) * 16 + lr];
#pragma unroll
    for (int er = 0; er < 4; ++er) {
#pragma unroll
        for (int j = 0; j < 2; ++j) {
            float bb = j ? bb1 : bb0;
            int feat = (wv * 2 + j) * 16 + lr;
#pragma unroll
            for (int r = 0; r < 4; ++r) {
                int node = nbase + er * 16 + lg * 4 + r;
                if (node < N_NODES) {
                    size_t idx = (size_t)node * H + feat;
                    float nm = nmask[node];
                    float v = (h_cur[idx] + acc2[er][j][r] + bb) * nm;  // fp32 residual
                    h_cur[idx] = v;
                    h_bf[idx] = (bf16)v;
                }
            }
        }
    }
}

// ---------------- launch ----------------
extern "C" void kernel_launch(void* const* d_in, const int* in_sizes, int n_in,
                              void* d_out, int out_size, void* d_ws, size_t ws_size,
                              hipStream_t stream) {
    (void)in_sizes; (void)n_in; (void)out_size; (void)ws_size;
    const float* h_in  = (const float*)d_in[0];
    const float* x_in  = (const float*)d_in[1];
    const int*   ei    = (const int*)d_in[2];
    const float* eattr = (const float*)d_in[3];
    const float* nmask = (const float*)d_in[4];
    const float* emask = (const float*)d_in[5];
    const float* e_w1  = (const float*)d_in[6];
    const float* e_b1  = (const float*)d_in[7];
    const float* e_w2  = (const float*)d_in[8];
    const float* e_b2  = (const float*)d_in[9];
    const float* a_w   = (const float*)d_in[10];
    const float* a_b   = (const float*)d_in[11];
    const float* n_w1  = (const float*)d_in[12];
    const float* n_b1  = (const float*)d_in[13];
    const float* n_w2  = (const float*)d_in[14];
    const float* n_b2  = (const float*)d_in[15];
    const float* c_w1  = (const float*)d_in[16];
    const float* c_b1  = (const float*)d_in[17];
    const float* c_w2  = (const float*)d_in[18];
    const float* c_b2  = (const float*)d_in[19];
    const float* c_w3  = (const float*)d_in[20];
    float* out = (float*)d_out;

    char* p = (char*)d_ws;
    auto alloc = [&](size_t bytes) { char* r = p; p += (bytes + 255) & ~(size_t)255; return r; };
    float* h_cur  = (float*)alloc((size_t)N_NODES * H * 4);
    bf16*  h_bf   = (bf16*) alloc((size_t)N_NODES * H * 2);
    bf16*  agg_bf = (bf16*) alloc((size_t)N_NODES * H * 2);
    bf16*  ea_bf  = (bf16*) alloc((size_t)N_EDGES * 2 * 2);
    bf16*  ef     = (bf16*) alloc((size_t)N_EDGES * H * 2);   // 204.8 MB
    float* trans  = (float*)ef;                               // alias: ef dead before edge<1>
    int*   deg    = (int*)  alloc((size_t)N_NODES * 4);
    int*   off    = (int*)  alloc((size_t)N_NODES * 4);
    int*   cursor = (int*)  alloc((size_t)N_NODES * 4);
    int*   bsum   = (int*)  alloc((size_t)NB_SCAN * 4);
    int*   eids   = (int*)  alloc((size_t)N_EDGES * 4);
    bf16*  e_w1t  = (bf16*) alloc((size_t)2 * 128 * 288 * 2);
    bf16*  e_w2t  = (bf16*) alloc((size_t)2 * 128 * 128 * 2);
    bf16*  n_w1t  = (bf16*) alloc((size_t)2 * 128 * 256 * 2);
    bf16*  n_w2t  = (bf16*) alloc((size_t)2 * 128 * 128 * 2);
    bf16*  c_w1t  = (bf16*) alloc((size_t)128 * 288 * 2);
    bf16*  c_w2t  = (bf16*) alloc((size_t)128 * 128 * 2);

    auto tp = [&](bf16* dst, const float* src, int K, int KP) {
        int tot = 128 * KP;
        transpose_pad_kernel<<<(tot + 255) / 256, 256, 0, stream>>>(dst, src, K, 128, KP);
    };
    tp(e_w1t, e_w1, 258, 288);               tp(e_w1t + 128 * 288, e_w1 + 258 * 128, 258, 288);
    tp(e_w2t, e_w2, 128, 128);               tp(e_w2t + 128 * 128, e_w2 + 128 * 128, 128, 128);
    tp(n_w1t, n_w1, 256, 256);               tp(n_w1t + 128 * 256, n_w1 + 256 * 128, 256, 256);
    tp(n_w2t, n_w2, 128, 128);               tp(n_w2t + 128 * 128, n_w2 + 128 * 128, 128, 128);
    tp(c_w1t, c_w1, 258, 288);
    tp(c_w2t, c_w2, 128, 128);

    h_init_kernel<<<(N_NODES * H + 255) / 256, 256, 0, stream>>>(h_in, h_cur, h_bf, N_NODES * H);
    ea_kernel<<<(N_EDGES + 255) / 256, 256, 0, stream>>>(x_in, ei, eattr, ea_bf);

    // ---- CSR build ----
    hipMemsetAsync(deg, 0, (size_t)N_NODES * 4, stream);
    count_kernel<<<(N_EDGES + 255) / 256, 256, 0, stream>>>(ei, deg);
    scan1_kernel<<<NB_SCAN, 256, 0, stream>>>(deg, off, bsum);
    scan2_kernel<<<1, 256, 0, stream>>>(bsum);
    scan3_kernel<<<NB_SCAN, 256, 0, stream>>>(off, cursor, bsum);
    fill_kernel<<<(N_EDGES + 255) / 256, 256, 0, stream>>>(ei, cursor, eids);

    int ngrid = (N_NODES + 3) / 4;
    for (int i = 0; i < 2; ++i) {
        edge_kernel<0><<<N_EDGES / 64, 256, 0, stream>>>(
            h_bf, ea_bf, ei, emask,
            e_w1t + (size_t)i * 128 * 288, e_b1 + i * H,
            e_w2t + (size_t)i * 128 * 128, e_b2 + i * H,
            a_w + i * H, a_b + i, nullptr, ef, nullptr);
        gather_h_kernel<<<ngrid, 256, 0, stream>>>(ef, off, deg, eids, agg_bf);
        node_kernel<<<(N_NODES + 63) / 64, 256, 0, stream>>>(
            h_cur, h_bf, agg_bf,
            n_w1t + (size_t)i * 128 * 256, n_b1 + i * H,
            n_w2t + (size_t)i * 128 * 128, n_b2 + i * H, nmask);
    }
    edge_kernel<1><<<N_EDGES / 64, 256, 0, stream>>>(
        h_bf, ea_bf, ei, emask,
        c_w1t, c_b1, c_w2t, c_b2, c_w3, nullptr, x_in, nullptr, trans);
    gather_x_kernel<<<ngrid, 256, 0, stream>>>(trans, off, deg, eids, x_in, nmask,
                                               out + (size_t)N_NODES * H);

    out_h_kernel<<<(N_NODES * H + 255) / 256, 256, 0, stream>>>(h_cur, nmask, out);
}

// Round 6
// 977.374 us; speedup vs baseline: 1.4777x; 1.1616x over previous
//
#include <hip/hip_runtime.h>
#include <hip/hip_bf16.h>
#include <math.h>
#include <string.h>

#define DEV __device__ __forceinline__

typedef __bf16 bf16;
typedef bf16 bf16x8 __attribute__((ext_vector_type(8)));
typedef bf16 bf16x2 __attribute__((ext_vector_type(2)));
typedef float f32x4 __attribute__((ext_vector_type(4)));
typedef unsigned int uint;

constexpr int N_NODES = 50000;
constexpr int N_EDGES = 800000;
constexpr int H = 128;
constexpr int NB_SCAN = (N_NODES + 255) / 256;  // 196

DEV float fsilu(float x) { return x / (1.f + __expf(-x)); }
DEV float fsigmoid(float x) { return 1.f / (1.f + __expf(-x)); }

// ---------------- small prep kernels ----------------

__global__ void transpose_pad_kernel(bf16* __restrict__ dst, const float* __restrict__ src,
                                     int K, int Nf, int KP) {
    int idx = blockIdx.x * 256 + threadIdx.x;
    if (idx >= Nf * KP) return;
    int n = idx / KP, k = idx - n * KP;
    dst[idx] = (k < K) ? (bf16)src[k * Nf + n] : (bf16)0.f;
}

__global__ void h_init_kernel(const float* __restrict__ h, float* __restrict__ h_cur,
                              bf16* __restrict__ h_bf, int n) {
    int i = blockIdx.x * 256 + threadIdx.x;
    if (i < n) { float v = h[i]; h_cur[i] = v; h_bf[i] = (bf16)v; }
}

__global__ void ea_kernel(const float* __restrict__ x, const int* __restrict__ ei,
                          const float* __restrict__ eattr, bf16* __restrict__ ea_bf) {
    int e = blockIdx.x * 256 + threadIdx.x;
    if (e >= N_EDGES) return;
    int r = ei[e], c = ei[N_EDGES + e];
    float dx = x[r * 3 + 0] - x[c * 3 + 0];
    float dy = x[r * 3 + 1] - x[c * 3 + 1];
    float dz = x[r * 3 + 2] - x[c * 3 + 2];
    float radial = dx * dx + dy * dy + dz * dz;
    ea_bf[e * 2 + 0] = (bf16)radial;
    ea_bf[e * 2 + 1] = (bf16)eattr[e];
}

__global__ void out_h_kernel(const float* __restrict__ h_cur, const float* __restrict__ nmask,
                             float* __restrict__ out) {
    int i = blockIdx.x * 256 + threadIdx.x;
    if (i < N_NODES * H) out[i] = h_cur[i] * nmask[i >> 7];
}

// ---------------- CSR build (group edges by row) ----------------

__global__ void count_kernel(const int* __restrict__ ei, int* __restrict__ deg) {
    int e = blockIdx.x * 256 + threadIdx.x;
    if (e < N_EDGES) atomicAdd(&deg[ei[e]], 1);
}

__global__ void scan1_kernel(const int* __restrict__ deg, int* __restrict__ off,
                             int* __restrict__ bsum) {
    __shared__ int s[256];
    int t = threadIdx.x, i = blockIdx.x * 256 + t;
    int v = (i < N_NODES) ? deg[i] : 0;
    s[t] = v;
    __syncthreads();
#pragma unroll
    for (int st = 1; st < 256; st <<= 1) {
        int x = (t >= st) ? s[t - st] : 0;
        __syncthreads();
        s[t] += x;
        __syncthreads();
    }
    if (i < N_NODES) off[i] = s[t] - v;
    if (t == 255) bsum[blockIdx.x] = s[255];
}

__global__ void scan2_kernel(int* __restrict__ bsum) {
    __shared__ int s[256];
    int t = threadIdx.x;
    int v = (t < NB_SCAN) ? bsum[t] : 0;
    s[t] = v;
    __syncthreads();
#pragma unroll
    for (int st = 1; st < 256; st <<= 1) {
        int x = (t >= st) ? s[t - st] : 0;
        __syncthreads();
        s[t] += x;
        __syncthreads();
    }
    if (t < NB_SCAN) bsum[t] = s[t] - v;
}

__global__ void scan3_kernel(int* __restrict__ off, int* __restrict__ cursor,
                             const int* __restrict__ bsum) {
    int i = blockIdx.x * 256 + threadIdx.x;
    if (i >= N_NODES) return;
    int o = off[i] + bsum[blockIdx.x];
    off[i] = o;
    cursor[i] = o;
}

__global__ void fill_kernel(const int* __restrict__ ei, int* __restrict__ cursor,
                            int* __restrict__ eids) {
    int e = blockIdx.x * 256 + threadIdx.x;
    if (e >= N_EDGES) return;
    int slot = atomicAdd(&cursor[ei[e]], 1);
    eids[slot] = e;
}

// ---------------- gathers ----------------

__global__ __launch_bounds__(256) void gather_h_kernel(
    const bf16* __restrict__ ef, const int* __restrict__ off, const int* __restrict__ deg,
    const int* __restrict__ eids, bf16* __restrict__ agg_bf) {
    int t = threadIdx.x, lane = t & 63, wv = t >> 6;
    int n = blockIdx.x * 4 + wv;
    if (n >= N_NODES) return;
    int st = off[n], dg = deg[n];
    float s0 = 0.f, s1 = 0.f;
    for (int k = 0; k < dg; ++k) {
        int e = eids[st + k];
        uint v = *(const uint*)(ef + (size_t)e * H + lane * 2);
        s0 += __uint_as_float(v << 16);
        s1 += __uint_as_float(v & 0xffff0000u);
    }
    bf16x2 o;
    o[0] = (bf16)(s0 * 0.01f);
    o[1] = (bf16)(s1 * 0.01f);
    *(bf16x2*)(agg_bf + (size_t)n * H + lane * 2) = o;
}

__global__ __launch_bounds__(256) void gather_x_kernel(
    const float* __restrict__ trans, const int* __restrict__ off, const int* __restrict__ deg,
    const int* __restrict__ eids, const float* __restrict__ x, const float* __restrict__ nmask,
    float* __restrict__ outx) {
    int t = threadIdx.x, lane = t & 63, wv = t >> 6;
    int n = blockIdx.x * 4 + wv;
    if (n >= N_NODES) return;
    int st = off[n], dg = deg[n];
    float sx = 0.f, sy = 0.f, sz = 0.f;
    for (int k = lane; k < dg; k += 64) {
        int e = eids[st + k];
        sx += trans[e * 3 + 0];
        sy += trans[e * 3 + 1];
        sz += trans[e * 3 + 2];
    }
#pragma unroll
    for (int m = 1; m < 64; m <<= 1) {
        sx += __shfl_xor(sx, m);
        sy += __shfl_xor(sy, m);
        sz += __shfl_xor(sz, m);
    }
    if (lane == 0) {
        float nm = nmask[n];
        outx[n * 3 + 0] = (x[n * 3 + 0] + sx * 0.01f) * nm;
        outx[n * 3 + 1] = (x[n * 3 + 1] + sy * 0.01f) * nm;
        outx[n * 3 + 2] = (x[n * 3 + 2] + sz * 0.01f) * nm;
    }
}

// ---------------- MFMA helpers ----------------
// A layout (16x16x32 bf16): lane holds A[lane&15][(lane>>4)*8 + i]
// C/D layout (HW-verified): col = lane&15, row = (lane>>4)*4 + reg

template <int KCHUNKS, int ASTRIDE, int BSTRIDE>
DEV void wave_gemm(const bf16* A_lds, const bf16* __restrict__ Bt,
                   f32x4 (&acc)[4][2], int lr, int lg, int wv) {
#pragma unroll
    for (int kk = 0; kk < KCHUNKS; ++kk) {
        int ko = kk * 32 + lg * 8;
        bf16x8 a[4], b[2];
#pragma unroll
        for (int er = 0; er < 4; ++er)
            a[er] = *(const bf16x8*)(A_lds + (er * 16 + lr) * ASTRIDE + ko);
#pragma unroll
        for (int j = 0; j < 2; ++j)
            b[j] = *(const bf16x8*)(Bt + (size_t)((wv * 2 + j) * 16 + lr) * BSTRIDE + ko);
#pragma unroll
        for (int er = 0; er < 4; ++er)
#pragma unroll
            for (int j = 0; j < 2; ++j)
                acc[er][j] = __builtin_amdgcn_mfma_f32_16x16x32_bf16(a[er], b[j], acc[er][j], 0, 0, 0);
    }
}

DEV void epi_silu_store(const f32x4 (&acc)[4][2], const float* __restrict__ bias,
                        bf16* out_lds, int OSTRIDE, int lr, int lg, int wv) {
    float b0 = bias[(wv * 2 + 0) * 16 + lr];
    float b1 = bias[(wv * 2 + 1) * 16 + lr];
#pragma unroll
    for (int er = 0; er < 4; ++er) {
#pragma unroll
        for (int j = 0; j < 2; ++j) {
            float bb = j ? b1 : b0;
            int fcol = (wv * 2 + j) * 16 + lr;
#pragma unroll
            for (int r = 0; r < 4; ++r) {
                int rrow = er * 16 + lg * 4 + r;
                out_lds[rrow * OSTRIDE + fcol] = (bf16)fsilu(acc[er][j][r] + bb);
            }
        }
    }
}

// swizzled variant: [64][128] with 16B-slot XOR (slot ^= row&7)
DEV void epi_silu_store_swz(const f32x4 (&acc)[4][2], const float* __restrict__ bias,
                            bf16* out_lds, int lr, int lg, int wv) {
    float b0 = bias[(wv * 2 + 0) * 16 + lr];
    float b1 = bias[(wv * 2 + 1) * 16 + lr];
#pragma unroll
    for (int er = 0; er < 4; ++er) {
#pragma unroll
        for (int j = 0; j < 2; ++j) {
            float bb = j ? b1 : b0;
            int fcol = (wv * 2 + j) * 16 + lr;
#pragma unroll
            for (int r = 0; r < 4; ++r) {
                int rrow = er * 16 + lg * 4 + r;
                int sl = (fcol >> 3) ^ (rrow & 7);
                out_lds[rrow * 128 + sl * 8 + (fcol & 7)] = (bf16)fsilu(acc[er][j][r] + bb);
            }
        }
    }
}

// ---------------- edge / coord kernel ----------------
// Staging: async global_load_lds (16B/lane) into AR/AC [64][128], XOR slot swizzle
// applied on the GLOBAL source (linear LDS dest). ea K-tail in registers (kk=8).
// LDS reuse: AR (h[row]) becomes t1 = silu(GEMM1) after a barrier; AC (h[col])
// becomes mij after GEMM1. Total LDS ~33.3 KB -> 4 blocks/CU.
// MODE 0: GCL edge MLP + attention -> ef[e][128] bf16
// MODE 1: coord MLP -> phi -> trans[e][3] f32
template <int MODE>
__global__ __launch_bounds__(256, 4) void edge_kernel(
    const bf16* __restrict__ h_bf, const bf16* __restrict__ ea_bf,
    const int* __restrict__ ei, const float* __restrict__ emask,
    const bf16* __restrict__ w1t, const float* __restrict__ b1,
    const bf16* __restrict__ w2t, const float* __restrict__ b2,
    const float* __restrict__ avec, const float* __restrict__ abias,
    const float* __restrict__ xg, bf16* __restrict__ efout, float* __restrict__ trans) {
    __shared__ __align__(16) bf16 AR[64 * 128];   // h[row] tile -> reused as t1 (swz)
    __shared__ __align__(16) bf16 AC[64 * 128];   // h[col] tile -> reused as mij (swz)
    __shared__ __align__(16) float avec_l[128];
    __shared__ int row_l[64];
    __shared__ int col_l[64];
    __shared__ float em_l[64];

    int t = threadIdx.x, lane = t & 63, wv = t >> 6;
    int lr = lane & 15, lg = lane >> 4;
    int ebase = blockIdx.x * 64;

    {   // async stage: each instr writes 4 rows x 256B = 1024B linear LDS
        int rsub = lane >> 4;     // row within 4-row group
        int slot = lane & 15;     // 16B slot within row
#pragma unroll
        for (int u = 0; u < 4; ++u) {
            int r = wv * 16 + u * 4 + rsub;
            int nr = ei[ebase + r];
            int sl = slot ^ (r & 7);   // pre-swizzled source
            const bf16* gp = h_bf + (size_t)nr * H + sl * 8;
            __builtin_amdgcn_global_load_lds(
                (const __attribute__((address_space(1))) void*)gp,
                (__attribute__((address_space(3))) void*)&AR[(wv * 16 + u * 4) * 128],
                16, 0, 0);
        }
#pragma unroll
        for (int u = 0; u < 4; ++u) {
            int r = wv * 16 + u * 4 + rsub;
            int nc = ei[N_EDGES + ebase + r];
            int sl = slot ^ (r & 7);
            const bf16* gp = h_bf + (size_t)nc * H + sl * 8;
            __builtin_amdgcn_global_load_lds(
                (const __attribute__((address_space(1))) void*)gp,
                (__attribute__((address_space(3))) void*)&AC[(wv * 16 + u * 4) * 128],
                16, 0, 0);
        }
    }
    if (t < 64) {
        int e = ebase + t;
        row_l[t] = ei[e];
        col_l[t] = ei[N_EDGES + e];
        em_l[t] = emask[e];
    } else if (t < 192) {
        avec_l[t - 64] = avec[t - 64];
    }

    // ea K-tail in registers
    uint eau[4];
#pragma unroll
    for (int er = 0; er < 4; ++er)
        eau[er] = *(const uint*)(ea_bf + (size_t)(ebase + er * 16 + lr) * 2);

    const bf16* bp0 = w1t + (size_t)((wv * 2 + 0) * 16 + lr) * 288 + lg * 8;
    const bf16* bp1 = w1t + (size_t)((wv * 2 + 1) * 16 + lr) * 288 + lg * 8;

    __syncthreads();  // drains global_load_lds (vmcnt) + meta stores

    f32x4 acc[4][2];
#pragma unroll
    for (int er = 0; er < 4; ++er)
#pragma unroll
        for (int j = 0; j < 2; ++j) acc[er][j] = (f32x4)0.f;

    // kk 0..3: h[row] from AR; kk 4..7: h[col] from AC (swizzled reads)
#pragma unroll
    for (int kk = 0; kk < 8; ++kk) {
        const bf16* Ab = (kk < 4) ? AR : AC;
        int k4 = kk & 3;
        bf16x8 a[4], b[2];
        b[0] = *(const bf16x8*)(bp0 + kk * 32);
        b[1] = *(const bf16x8*)(bp1 + kk * 32);
#pragma unroll
        for (int er = 0; er < 4; ++er) {
            int sl = (k4 * 4 + lg) ^ (lr & 7);
            a[er] = *(const bf16x8*)(Ab + (er * 16 + lr) * 128 + sl * 8);
        }
#pragma unroll
        for (int er = 0; er < 4; ++er)
#pragma unroll
            for (int j = 0; j < 2; ++j)
                acc[er][j] = __builtin_amdgcn_mfma_f32_16x16x32_bf16(a[er], b[j], acc[er][j], 0, 0, 0);
    }
    {   // kk 8: [radial, edge_attr, 0...] fragment (nonzero only for lg==0)
        bf16x8 a[4], b[2];
        b[0] = *(const bf16x8*)(bp0 + 8 * 32);
        b[1] = *(const bf16x8*)(bp1 + 8 * 32);
#pragma unroll
        for (int er = 0; er < 4; ++er) {
            bf16x8 f = (bf16x8)(bf16)0.f;
            if (lg == 0) {
                bf16x2 ep;
                memcpy(&ep, &eau[er], 4);
                f[0] = ep[0];
                f[1] = ep[1];
            }
            a[er] = f;
        }
#pragma unroll
        for (int er = 0; er < 4; ++er)
#pragma unroll
            for (int j = 0; j < 2; ++j)
                acc[er][j] = __builtin_amdgcn_mfma_f32_16x16x32_bf16(a[er], b[j], acc[er][j], 0, 0, 0);
    }
    __syncthreads();  // all waves done reading AR (and AC) in GEMM1

    // t1 = silu(GEMM1) -> AR (swizzled [64][128])
    epi_silu_store_swz(acc, b1, AR, lr, lg, wv);
    __syncthreads();  // t1 ready

    // GEMM2: A = t1 (AR, swz), B = w2t
    f32x4 acc2[4][2];
#pragma unroll
    for (int er = 0; er < 4; ++er)
#pragma unroll
        for (int j = 0; j < 2; ++j) acc2[er][j] = (f32x4)0.f;
    {
        const bf16* cp0 = w2t + (size_t)((wv * 2 + 0) * 16 + lr) * 128 + lg * 8;
        const bf16* cp1 = w2t + (size_t)((wv * 2 + 1) * 16 + lr) * 128 + lg * 8;
#pragma unroll
        for (int kk = 0; kk < 4; ++kk) {
            bf16x8 a[4], b[2];
            b[0] = *(const bf16x8*)(cp0 + kk * 32);
            b[1] = *(const bf16x8*)(cp1 + kk * 32);
#pragma unroll
            for (int er = 0; er < 4; ++er) {
                int sl = (kk * 4 + lg) ^ (lr & 7);
                a[er] = *(const bf16x8*)(AR + (er * 16 + lr) * 128 + sl * 8);
            }
#pragma unroll
            for (int er = 0; er < 4; ++er)
#pragma unroll
                for (int j = 0; j < 2; ++j)
                    acc2[er][j] = __builtin_amdgcn_mfma_f32_16x16x32_bf16(a[er], b[j], acc2[er][j], 0, 0, 0);
        }
    }

    bf16* mij = AC;  // safe: all GEMM1 AC reads completed before the pre-epi1 barrier
    epi_silu_store_swz(acc2, b2, mij, lr, lg, wv);
    __syncthreads();

    // per-edge dot over 128 feats: 4 threads/edge, shfl reduce (swizzled mij reads)
    int el = t >> 2, q = t & 3;
    float part = 0.f;
    bf16x8 mv[4];
#pragma unroll
    for (int c = 0; c < 4; ++c) {
        int sl = (q * 4 + c) ^ (el & 7);
        mv[c] = *(const bf16x8*)(mij + el * 128 + sl * 8);
        f32x4 av0 = *(const f32x4*)(avec_l + q * 32 + c * 8);
        f32x4 av1 = *(const f32x4*)(avec_l + q * 32 + c * 8 + 4);
#pragma unroll
        for (int jj = 0; jj < 4; ++jj) part += (float)mv[c][jj] * av0[jj];
#pragma unroll
        for (int jj = 0; jj < 4; ++jj) part += (float)mv[c][4 + jj] * av1[jj];
    }
    part += __shfl_xor(part, 1);
    part += __shfl_xor(part, 2);

    if (MODE == 0) {
        float att = fsigmoid(part + abias[0]);
        float scale = att * em_l[el];
        bf16* edst = efout + (size_t)(ebase + el) * H + q * 32;
#pragma unroll
        for (int c = 0; c < 4; ++c) {
            bf16x8 o;
#pragma unroll
            for (int jj = 0; jj < 8; ++jj) o[jj] = (bf16)((float)mv[c][jj] * scale);
            *(bf16x8*)(edst + c * 8) = o;
        }
    } else {
        if (q == 0) {
            int rr = row_l[el], cc = col_l[el];
            float dx = xg[rr * 3 + 0] - xg[cc * 3 + 0];
            float dy = xg[rr * 3 + 1] - xg[cc * 3 + 1];
            float dz = xg[rr * 3 + 2] - xg[cc * 3 + 2];
            float radial = dx * dx + dy * dy + dz * dz;
            float inv = 1.f / (sqrtf(radial + 1e-8f) + 1.f);
            float s = part * em_l[el] * inv;
            int e = ebase + el;
            trans[e * 3 + 0] = dx * s;
            trans[e * 3 + 1] = dy * s;
            trans[e * 3 + 2] = dz * s;
        }
    }
}

// ---------------- node MLP kernel ----------------
__global__ __launch_bounds__(256, 2) void node_kernel(
    float* __restrict__ h_cur, bf16* __restrict__ h_bf, const bf16* __restrict__ agg_bf,
    const bf16* __restrict__ w1t, const float* __restrict__ b1,
    const bf16* __restrict__ w2t, const float* __restrict__ b2,
    const float* __restrict__ nmask) {
    constexpr int SRN = 264;
    constexpr int TRN = 136;
    __shared__ __align__(16) bf16 ninp[64 * SRN];
    __shared__ __align__(16) bf16 t1[64 * TRN];

    int t = threadIdx.x, lane = t & 63, wv = t >> 6;
    int lr = lane & 15, lg = lane >> 4;
    int nbase = blockIdx.x * 64;

    {   // stage ninp = [bf16(h), agg_bf]
        int nl = t >> 2, q = t & 3;
        int node = nbase + nl;
        bf16* dst = ninp + nl * SRN;
        if (node < N_NODES) {
            const float4* hr = (const float4*)(h_cur + (size_t)node * H);
            const bf16* ar = agg_bf + (size_t)node * H;
#pragma unroll
            for (int pp = 0; pp < 8; ++pp) {
                int ch = pp * 4 + q;
                float4 v = hr[ch];
                dst[ch * 4 + 0] = (bf16)v.x; dst[ch * 4 + 1] = (bf16)v.y;
                dst[ch * 4 + 2] = (bf16)v.z; dst[ch * 4 + 3] = (bf16)v.w;
            }
#pragma unroll
            for (int pp = 0; pp < 4; ++pp) {
                int ch = pp * 4 + q;
                *(bf16x8*)(dst + 128 + ch * 8) = *(const bf16x8*)(ar + ch * 8);
            }
        } else {
#pragma unroll
            for (int pp = 0; pp < 8; ++pp) {
                int ch = pp * 4 + q;
#pragma unroll
                for (int k = 0; k < 4; ++k) {
                    dst[ch * 4 + k] = (bf16)0.f;
                    dst[128 + ch * 4 + k] = (bf16)0.f;
                }
            }
        }
    }
    __syncthreads();

    f32x4 acc[4][2];
#pragma unroll
    for (int er = 0; er < 4; ++er)
#pragma unroll
        for (int j = 0; j < 2; ++j) acc[er][j] = (f32x4)0.f;
    wave_gemm<8, SRN, 256>(ninp, w1t, acc, lr, lg, wv);
    epi_silu_store(acc, b1, t1, TRN, lr, lg, wv);
    __syncthreads();

    f32x4 acc2[4][2];
#pragma unroll
    for (int er = 0; er < 4; ++er)
#pragma unroll
        for (int j = 0; j < 2; ++j) acc2[er][j] = (f32x4)0.f;
    wave_gemm<4, TRN, 128>(t1, w2t, acc2, lr, lg, wv);

    float bb0 = b2[(wv * 2 + 0) * 16 + lr];
    float bb1 = b2[(wv * 2 + 1) * 16 + lr];
#pragma unroll
    for (int er = 0; er < 4; ++er) {
#pragma unroll
        for (int j = 0; j < 2; ++j) {
            float bb = j ? bb1 : bb0;
            int feat = (wv * 2 + j) * 16 + lr;
#pragma unroll
            for (int r = 0; r < 4; ++r) {
                int node = nbase + er * 16 + lg * 4 + r;
                if (node < N_NODES) {
                    size_t idx = (size_t)node * H + feat;
                    float nm = nmask[node];
                    float v = (h_cur[idx] + acc2[er][j][r] + bb) * nm;  // fp32 residual
                    h_cur[idx] = v;
                    h_bf[idx] = (bf16)v;
                }
            }
        }
    }
}

// ---------------- launch ----------------
extern "C" void kernel_launch(void* const* d_in, const int* in_sizes, int n_in,
                              void* d_out, int out_size, void* d_ws, size_t ws_size,
                              hipStream_t stream) {
    (void)in_sizes; (void)n_in; (void)out_size; (void)ws_size;
    const float* h_in  = (const float*)d_in[0];
    const float* x_in  = (const float*)d_in[1];
    const int*   ei    = (const int*)d_in[2];
    const float* eattr = (const float*)d_in[3];
    const float* nmask = (const float*)d_in[4];
    const float* emask = (const float*)d_in[5];
    const float* e_w1  = (const float*)d_in[6];
    const float* e_b1  = (const float*)d_in[7];
    const float* e_w2  = (const float*)d_in[8];
    const float* e_b2  = (const float*)d_in[9];
    const float* a_w   = (const float*)d_in[10];
    const float* a_b   = (const float*)d_in[11];
    const float* n_w1  = (const float*)d_in[12];
    const float* n_b1  = (const float*)d_in[13];
    const float* n_w2  = (const float*)d_in[14];
    const float* n_b2  = (const float*)d_in[15];
    const float* c_w1  = (const float*)d_in[16];
    const float* c_b1  = (const float*)d_in[17];
    const float* c_w2  = (const float*)d_in[18];
    const float* c_b2  = (const float*)d_in[19];
    const float* c_w3  = (const float*)d_in[20];
    float* out = (float*)d_out;

    char* p = (char*)d_ws;
    auto alloc = [&](size_t bytes) { char* r = p; p += (bytes + 255) & ~(size_t)255; return r; };
    float* h_cur  = (float*)alloc((size_t)N_NODES * H * 4);
    bf16*  h_bf   = (bf16*) alloc((size_t)N_NODES * H * 2);
    bf16*  agg_bf = (bf16*) alloc((size_t)N_NODES * H * 2);
    bf16*  ea_bf  = (bf16*) alloc((size_t)N_EDGES * 2 * 2);
    bf16*  ef     = (bf16*) alloc((size_t)N_EDGES * H * 2);   // 204.8 MB
    float* trans  = (float*)ef;                               // alias: ef dead before edge<1>
    int*   deg    = (int*)  alloc((size_t)N_NODES * 4);
    int*   off    = (int*)  alloc((size_t)N_NODES * 4);
    int*   cursor = (int*)  alloc((size_t)N_NODES * 4);
    int*   bsum   = (int*)  alloc((size_t)NB_SCAN * 4);
    int*   eids   = (int*)  alloc((size_t)N_EDGES * 4);
    bf16*  e_w1t  = (bf16*) alloc((size_t)2 * 128 * 288 * 2);
    bf16*  e_w2t  = (bf16*) alloc((size_t)2 * 128 * 128 * 2);
    bf16*  n_w1t  = (bf16*) alloc((size_t)2 * 128 * 256 * 2);
    bf16*  n_w2t  = (bf16*) alloc((size_t)2 * 128 * 128 * 2);
    bf16*  c_w1t  = (bf16*) alloc((size_t)128 * 288 * 2);
    bf16*  c_w2t  = (bf16*) alloc((size_t)128 * 128 * 2);

    auto tp = [&](bf16* dst, const float* src, int K, int KP) {
        int tot = 128 * KP;
        transpose_pad_kernel<<<(tot + 255) / 256, 256, 0, stream>>>(dst, src, K, 128, KP);
    };
    tp(e_w1t, e_w1, 258, 288);               tp(e_w1t + 128 * 288, e_w1 + 258 * 128, 258, 288);
    tp(e_w2t, e_w2, 128, 128);               tp(e_w2t + 128 * 128, e_w2 + 128 * 128, 128, 128);
    tp(n_w1t, n_w1, 256, 256);               tp(n_w1t + 128 * 256, n_w1 + 256 * 128, 256, 256);
    tp(n_w2t, n_w2, 128, 128);               tp(n_w2t + 128 * 128, n_w2 + 128 * 128, 128, 128);
    tp(c_w1t, c_w1, 258, 288);
    tp(c_w2t, c_w2, 128, 128);

    h_init_kernel<<<(N_NODES * H + 255) / 256, 256, 0, stream>>>(h_in, h_cur, h_bf, N_NODES * H);
    ea_kernel<<<(N_EDGES + 255) / 256, 256, 0, stream>>>(x_in, ei, eattr, ea_bf);

    // ---- CSR build ----
    hipMemsetAsync(deg, 0, (size_t)N_NODES * 4, stream);
    count_kernel<<<(N_EDGES + 255) / 256, 256, 0, stream>>>(ei, deg);
    scan1_kernel<<<NB_SCAN, 256, 0, stream>>>(deg, off, bsum);
    scan2_kernel<<<1, 256, 0, stream>>>(bsum);
    scan3_kernel<<<NB_SCAN, 256, 0, stream>>>(off, cursor, bsum);
    fill_kernel<<<(N_EDGES + 255) / 256, 256, 0, stream>>>(ei, cursor, eids);

    int ngrid = (N_NODES + 3) / 4;
    for (int i = 0; i < 2; ++i) {
        edge_kernel<0><<<N_EDGES / 64, 256, 0, stream>>>(
            h_bf, ea_bf, ei, emask,
            e_w1t + (size_t)i * 128 * 288, e_b1 + i * H,
            e_w2t + (size_t)i * 128 * 128, e_b2 + i * H,
            a_w + i * H, a_b + i, nullptr, ef, nullptr);
        gather_h_kernel<<<ngrid, 256, 0, stream>>>(ef, off, deg, eids, agg_bf);
        node_kernel<<<(N_NODES + 63) / 64, 256, 0, stream>>>(
            h_cur, h_bf, agg_bf,
            n_w1t + (size_t)i * 128 * 256, n_b1 + i * H,
            n_w2t + (size_t)i * 128 * 128, n_b2 + i * H, nmask);
    }
    edge_kernel<1><<<N_EDGES / 64, 256, 0, stream>>>(
        h_bf, ea_bf, ei, emask,
        c_w1t, c_b1, c_w2t, c_b2, c_w3, nullptr, x_in, nullptr, trans);
    gather_x_kernel<<<ngrid, 256, 0, stream>>>(trans, off, deg, eids, x_in, nmask,
                                               out + (size_t)N_NODES * H);

    out_h_kernel<<<(N_NODES * H + 255) / 256, 256, 0, stream>>>(h_cur, nmask, out);
}

// Round 9
// 957.274 us; speedup vs baseline: 1.5087x; 1.0210x over previous
//
#include <hip/hip_runtime.h>
#include <hip/hip_bf16.h>
#include <math.h>
#include <string.h>

#define DEV __device__ __forceinline__

typedef __bf16 bf16;
typedef bf16 bf16x8 __attribute__((ext_vector_type(8)));
typedef bf16 bf16x2 __attribute__((ext_vector_type(2)));
typedef float f32x4 __attribute__((ext_vector_type(4)));
typedef unsigned int uint;

constexpr int N_NODES = 50000;
constexpr int N_EDGES = 800000;
constexpr int H = 128;
constexpr int NB_SCAN = (N_NODES + 255) / 256;  // 196

DEV float fsilu(float x) { return x / (1.f + __expf(-x)); }
DEV float fsigmoid(float x) { return 1.f / (1.f + __expf(-x)); }

// ---------------- small prep kernels ----------------

__global__ void transpose_pad_kernel(bf16* __restrict__ dst, const float* __restrict__ src,
                                     int K, int Nf, int KP) {
    int idx = blockIdx.x * 256 + threadIdx.x;
    if (idx >= Nf * KP) return;
    int n = idx / KP, k = idx - n * KP;
    dst[idx] = (k < K) ? (bf16)src[k * Nf + n] : (bf16)0.f;
}

__global__ void h_init_kernel(const float* __restrict__ h, float* __restrict__ h_cur,
                              bf16* __restrict__ h_bf, int n) {
    int i = blockIdx.x * 256 + threadIdx.x;
    if (i < n) { float v = h[i]; h_cur[i] = v; h_bf[i] = (bf16)v; }
}

__global__ void ea_kernel(const float* __restrict__ x, const int* __restrict__ ei,
                          const float* __restrict__ eattr, bf16* __restrict__ ea_bf) {
    int e = blockIdx.x * 256 + threadIdx.x;
    if (e >= N_EDGES) return;
    int r = ei[e], c = ei[N_EDGES + e];
    float dx = x[r * 3 + 0] - x[c * 3 + 0];
    float dy = x[r * 3 + 1] - x[c * 3 + 1];
    float dz = x[r * 3 + 2] - x[c * 3 + 2];
    float radial = dx * dx + dy * dy + dz * dz;
    ea_bf[e * 2 + 0] = (bf16)radial;
    ea_bf[e * 2 + 1] = (bf16)eattr[e];
}

__global__ void out_h_kernel(const float* __restrict__ h_cur, const float* __restrict__ nmask,
                             float* __restrict__ out) {
    int i = blockIdx.x * 256 + threadIdx.x;
    if (i < N_NODES * H) out[i] = h_cur[i] * nmask[i >> 7];
}

// ---------------- CSR build (group edges by row) ----------------

__global__ void count_kernel(const int* __restrict__ ei, int* __restrict__ deg) {
    int e = blockIdx.x * 256 + threadIdx.x;
    if (e < N_EDGES) atomicAdd(&deg[ei[e]], 1);
}

__global__ void scan1_kernel(const int* __restrict__ deg, int* __restrict__ off,
                             int* __restrict__ bsum) {
    __shared__ int s[256];
    int t = threadIdx.x, i = blockIdx.x * 256 + t;
    int v = (i < N_NODES) ? deg[i] : 0;
    s[t] = v;
    __syncthreads();
#pragma unroll
    for (int st = 1; st < 256; st <<= 1) {
        int x = (t >= st) ? s[t - st] : 0;
        __syncthreads();
        s[t] += x;
        __syncthreads();
    }
    if (i < N_NODES) off[i] = s[t] - v;
    if (t == 255) bsum[blockIdx.x] = s[255];
}

__global__ void scan2_kernel(int* __restrict__ bsum) {
    __shared__ int s[256];
    int t = threadIdx.x;
    int v = (t < NB_SCAN) ? bsum[t] : 0;
    s[t] = v;
    __syncthreads();
#pragma unroll
    for (int st = 1; st < 256; st <<= 1) {
        int x = (t >= st) ? s[t - st] : 0;
        __syncthreads();
        s[t] += x;
        __syncthreads();
    }
    if (t < NB_SCAN) bsum[t] = s[t] - v;
}

__global__ void scan3_kernel(int* __restrict__ off, int* __restrict__ cursor,
                             const int* __restrict__ bsum) {
    int i = blockIdx.x * 256 + threadIdx.x;
    if (i >= N_NODES) return;
    int o = off[i] + bsum[blockIdx.x];
    off[i] = o;
    cursor[i] = o;
}

__global__ void fill_kernel(const int* __restrict__ ei, int* __restrict__ cursor,
                            int* __restrict__ eids) {
    int e = blockIdx.x * 256 + threadIdx.x;
    if (e >= N_EDGES) return;
    int slot = atomicAdd(&cursor[ei[e]], 1);
    eids[slot] = e;
}

// ---------------- gathers (CSR-contiguous) ----------------

// agg_bf[n][:] = bf16( sum over contiguous ef rows [off[n], off[n]+deg[n]) * 0.01 )
__global__ __launch_bounds__(256) void gather_h_kernel(
    const bf16* __restrict__ ef, const int* __restrict__ off, const int* __restrict__ deg,
    bf16* __restrict__ agg_bf) {
    int t = threadIdx.x, lane = t & 63, wv = t >> 6;
    int n = blockIdx.x * 4 + wv;
    if (n >= N_NODES) return;
    int st = off[n], dg = deg[n];
    const bf16* bp = ef + (size_t)st * H + lane * 2;
    float s0 = 0.f, s1 = 0.f;
    for (int k = 0; k < dg; ++k) {
        uint v = *(const uint*)(bp + (size_t)k * H);
        s0 += __uint_as_float(v << 16);
        s1 += __uint_as_float(v & 0xffff0000u);
    }
    bf16x2 o;
    o[0] = (bf16)(s0 * 0.01f);
    o[1] = (bf16)(s1 * 0.01f);
    *(bf16x2*)(agg_bf + (size_t)n * H + lane * 2) = o;
}

__global__ __launch_bounds__(256) void gather_x_kernel(
    const float* __restrict__ trans, const int* __restrict__ off, const int* __restrict__ deg,
    const float* __restrict__ x, const float* __restrict__ nmask, float* __restrict__ outx) {
    int t = threadIdx.x, lane = t & 63, wv = t >> 6;
    int n = blockIdx.x * 4 + wv;
    if (n >= N_NODES) return;
    int st = off[n], dg = deg[n];
    float sx = 0.f, sy = 0.f, sz = 0.f;
    for (int k = lane; k < dg; k += 64) {
        const float* tp = trans + (size_t)(st + k) * 3;
        sx += tp[0];
        sy += tp[1];
        sz += tp[2];
    }
#pragma unroll
    for (int m = 1; m < 64; m <<= 1) {
        sx += __shfl_xor(sx, m);
        sy += __shfl_xor(sy, m);
        sz += __shfl_xor(sz, m);
    }
    if (lane == 0) {
        float nm = nmask[n];
        outx[n * 3 + 0] = (x[n * 3 + 0] + sx * 0.01f) * nm;
        outx[n * 3 + 1] = (x[n * 3 + 1] + sy * 0.01f) * nm;
        outx[n * 3 + 2] = (x[n * 3 + 2] + sz * 0.01f) * nm;
    }
}

// ---------------- MFMA helpers ----------------
// A layout (16x16x32 bf16): lane holds A[lane&15][(lane>>4)*8 + i]
// C/D layout (HW-verified): col = lane&15, row = (lane>>4)*4 + reg

template <int KCHUNKS, int ASTRIDE, int BSTRIDE>
DEV void wave_gemm(const bf16* A_lds, const bf16* __restrict__ Bt,
                   f32x4 (&acc)[4][2], int lr, int lg, int wv) {
#pragma unroll
    for (int kk = 0; kk < KCHUNKS; ++kk) {
        int ko = kk * 32 + lg * 8;
        bf16x8 a[4], b[2];
#pragma unroll
        for (int er = 0; er < 4; ++er)
            a[er] = *(const bf16x8*)(A_lds + (er * 16 + lr) * ASTRIDE + ko);
#pragma unroll
        for (int j = 0; j < 2; ++j)
            b[j] = *(const bf16x8*)(Bt + (size_t)((wv * 2 + j) * 16 + lr) * BSTRIDE + ko);
#pragma unroll
        for (int er = 0; er < 4; ++er)
#pragma unroll
            for (int j = 0; j < 2; ++j)
                acc[er][j] = __builtin_amdgcn_mfma_f32_16x16x32_bf16(a[er], b[j], acc[er][j], 0, 0, 0);
    }
}

DEV void epi_silu_store(const f32x4 (&acc)[4][2], const float* __restrict__ bias,
                        bf16* out_lds, int OSTRIDE, int lr, int lg, int wv) {
    float b0 = bias[(wv * 2 + 0) * 16 + lr];
    float b1 = bias[(wv * 2 + 1) * 16 + lr];
#pragma unroll
    for (int er = 0; er < 4; ++er) {
#pragma unroll
        for (int j = 0; j < 2; ++j) {
            float bb = j ? b1 : b0;
            int fcol = (wv * 2 + j) * 16 + lr;
#pragma unroll
            for (int r = 0; r < 4; ++r) {
                int rrow = er * 16 + lg * 4 + r;
                out_lds[rrow * OSTRIDE + fcol] = (bf16)fsilu(acc[er][j][r] + bb);
            }
        }
    }
}

// swizzled variant: [64][128] with 16B-slot XOR (slot ^= row&7)
DEV void epi_silu_store_swz(const f32x4 (&acc)[4][2], const float* __restrict__ bias,
                            bf16* out_lds, int lr, int lg, int wv) {
    float b0 = bias[(wv * 2 + 0) * 16 + lr];
    float b1 = bias[(wv * 2 + 1) * 16 + lr];
#pragma unroll
    for (int er = 0; er < 4; ++er) {
#pragma unroll
        for (int j = 0; j < 2; ++j) {
            float bb = j ? b1 : b0;
            int fcol = (wv * 2 + j) * 16 + lr;
#pragma unroll
            for (int r = 0; r < 4; ++r) {
                int rrow = er * 16 + lg * 4 + r;
                int sl = (fcol >> 3) ^ (rrow & 7);
                out_lds[rrow * 128 + sl * 8 + (fcol & 7)] = (bf16)fsilu(acc[er][j][r] + bb);
            }
        }
    }
}

// ---------------- edge / coord kernel (CSR-slot order via eids indirection) ----------------
// Block handles 64 consecutive CSR slots; e = eids[slot] gives the original edge.
// Consecutive slots share the same row node -> AR staging hits L1/L2, and ef/trans
// written at slot index -> gathers are contiguous. No permuted metadata arrays
// (workspace stays at the proven 263.5 MB). B-fragments kk=0..4 preloaded to regs.
// MODE 0: -> ef[slot][128] bf16. MODE 1: -> trans[slot][3] f32.
template <int MODE>
__global__ __launch_bounds__(256, 4) void edge_kernel(
    const bf16* __restrict__ h_bf, const bf16* __restrict__ ea_bf,
    const int* __restrict__ ei, const float* __restrict__ emask,
    const int* __restrict__ eids,
    const bf16* __restrict__ w1t, const float* __restrict__ b1,
    const bf16* __restrict__ w2t, const float* __restrict__ b2,
    const float* __restrict__ avec, const float* __restrict__ abias,
    const float* __restrict__ xg, bf16* __restrict__ efout, float* __restrict__ trans) {
    __shared__ __align__(16) bf16 AR[64 * 128];   // h[row] tile -> reused as t1 (swz)
    __shared__ __align__(16) bf16 AC[64 * 128];   // h[col] tile -> reused as mij (swz)
    __shared__ __align__(16) float avec_l[128];
    __shared__ int row_l[64];
    __shared__ int col_l[64];
    __shared__ float em_l[64];

    int t = threadIdx.x, lane = t & 63, wv = t >> 6;
    int lr = lane & 15, lg = lane >> 4;
    int ebase = blockIdx.x * 64;

    {   // async stage: each instr writes 4 rows x 256B = 1024B linear LDS
        int rsub = lane >> 4;     // row within 4-row group
        int slot = lane & 15;     // 16B slot within row
#pragma unroll
        for (int u = 0; u < 4; ++u) {
            int r = wv * 16 + u * 4 + rsub;
            int e = eids[ebase + r];
            int nr = ei[e];
            int nc = ei[N_EDGES + e];
            int sl = slot ^ (r & 7);   // pre-swizzled source
            const bf16* gpr = h_bf + (size_t)nr * H + sl * 8;
            __builtin_amdgcn_global_load_lds(
                (const __attribute__((address_space(1))) void*)gpr,
                (__attribute__((address_space(3))) void*)&AR[(wv * 16 + u * 4) * 128],
                16, 0, 0);
            const bf16* gpc = h_bf + (size_t)nc * H + sl * 8;
            __builtin_amdgcn_global_load_lds(
                (const __attribute__((address_space(1))) void*)gpc,
                (__attribute__((address_space(3))) void*)&AC[(wv * 16 + u * 4) * 128],
                16, 0, 0);
        }
    }
    if (t < 64) {
        int e = eids[ebase + t];
        row_l[t] = ei[e];
        col_l[t] = ei[N_EDGES + e];
        em_l[t] = emask[e];
    } else if (t < 192) {
        avec_l[t - 64] = avec[t - 64];
    }

    // ea K-tail in registers (slot -> edge indirection)
    uint eau[4];
#pragma unroll
    for (int er = 0; er < 4; ++er) {
        int e = eids[ebase + er * 16 + lr];
        eau[er] = *(const uint*)(ea_bf + (size_t)e * 2);
    }

    const bf16* bp0 = w1t + (size_t)((wv * 2 + 0) * 16 + lr) * 288 + lg * 8;
    const bf16* bp1 = w1t + (size_t)((wv * 2 + 1) * 16 + lr) * 288 + lg * 8;

    // preload B fragments kk=0..4 (overlaps staging latency; ~40 VGPR)
    bf16x8 bv0[5], bv1[5];
#pragma unroll
    for (int kk = 0; kk < 5; ++kk) {
        bv0[kk] = *(const bf16x8*)(bp0 + kk * 32);
        bv1[kk] = *(const bf16x8*)(bp1 + kk * 32);
    }

    __syncthreads();  // drains global_load_lds (vmcnt) + meta stores

    f32x4 acc[4][2];
#pragma unroll
    for (int er = 0; er < 4; ++er)
#pragma unroll
        for (int j = 0; j < 2; ++j) acc[er][j] = (f32x4)0.f;

    // kk 0..3: h[row] from AR; kk 4..7: h[col] from AC (swizzled reads)
#pragma unroll
    for (int kk = 0; kk < 8; ++kk) {
        const bf16* Ab = (kk < 4) ? AR : AC;
        int k4 = kk & 3;
        bf16x8 a[4], b[2];
        b[0] = (kk < 5) ? bv0[kk] : *(const bf16x8*)(bp0 + kk * 32);
        b[1] = (kk < 5) ? bv1[kk] : *(const bf16x8*)(bp1 + kk * 32);
#pragma unroll
        for (int er = 0; er < 4; ++er) {
            int sl = (k4 * 4 + lg) ^ (lr & 7);
            a[er] = *(const bf16x8*)(Ab + (er * 16 + lr) * 128 + sl * 8);
        }
#pragma unroll
        for (int er = 0; er < 4; ++er)
#pragma unroll
            for (int j = 0; j < 2; ++j)
                acc[er][j] = __builtin_amdgcn_mfma_f32_16x16x32_bf16(a[er], b[j], acc[er][j], 0, 0, 0);
    }
    {   // kk 8: [radial, edge_attr, 0...] fragment (nonzero only for lg==0)
        bf16x8 a[4], b[2];
        b[0] = *(const bf16x8*)(bp0 + 8 * 32);
        b[1] = *(const bf16x8*)(bp1 + 8 * 32);
#pragma unroll
        for (int er = 0; er < 4; ++er) {
            bf16x8 f = (bf16x8)(bf16)0.f;
            if (lg == 0) {
                bf16x2 ep;
                memcpy(&ep, &eau[er], 4);
                f[0] = ep[0];
                f[1] = ep[1];
            }
            a[er] = f;
        }
#pragma unroll
        for (int er = 0; er < 4; ++er)
#pragma unroll
            for (int j = 0; j < 2; ++j)
                acc[er][j] = __builtin_amdgcn_mfma_f32_16x16x32_bf16(a[er], b[j], acc[er][j], 0, 0, 0);
    }
    __syncthreads();  // all waves done reading AR (and AC) in GEMM1

    // t1 = silu(GEMM1) -> AR (swizzled [64][128])
    epi_silu_store_swz(acc, b1, AR, lr, lg, wv);
    __syncthreads();  // t1 ready

    // GEMM2: A = t1 (AR, swz), B = w2t
    f32x4 acc2[4][2];
#pragma unroll
    for (int er = 0; er < 4; ++er)
#pragma unroll
        for (int j = 0; j < 2; ++j) acc2[er][j] = (f32x4)0.f;
    {
        const bf16* cp0 = w2t + (size_t)((wv * 2 + 0) * 16 + lr) * 128 + lg * 8;
        const bf16* cp1 = w2t + (size_t)((wv * 2 + 1) * 16 + lr) * 128 + lg * 8;
#pragma unroll
        for (int kk = 0; kk < 4; ++kk) {
            bf16x8 a[4], b[2];
            b[0] = *(const bf16x8*)(cp0 + kk * 32);
            b[1] = *(const bf16x8*)(cp1 + kk * 32);
#pragma unroll
            for (int er = 0; er < 4; ++er) {
                int sl = (kk * 4 + lg) ^ (lr & 7);
                a[er] = *(const bf16x8*)(AR + (er * 16 + lr) * 128 + sl * 8);
            }
#pragma unroll
            for (int er = 0; er < 4; ++er)
#pragma unroll
                for (int j = 0; j < 2; ++j)
                    acc2[er][j] = __builtin_amdgcn_mfma_f32_16x16x32_bf16(a[er], b[j], acc2[er][j], 0, 0, 0);
        }
    }

    bf16* mij = AC;  // safe: all GEMM1 AC reads completed before the pre-epi1 barrier
    epi_silu_store_swz(acc2, b2, mij, lr, lg, wv);
    __syncthreads();

    // per-edge dot over 128 feats: 4 threads/edge, shfl reduce (swizzled mij reads)
    int el = t >> 2, q = t & 3;
    float part = 0.f;
    bf16x8 mv[4];
#pragma unroll
    for (int c = 0; c < 4; ++c) {
        int sl = (q * 4 + c) ^ (el & 7);
        mv[c] = *(const bf16x8*)(mij + el * 128 + sl * 8);
        f32x4 av0 = *(const f32x4*)(avec_l + q * 32 + c * 8);
        f32x4 av1 = *(const f32x4*)(avec_l + q * 32 + c * 8 + 4);
#pragma unroll
        for (int jj = 0; jj < 4; ++jj) part += (float)mv[c][jj] * av0[jj];
#pragma unroll
        for (int jj = 0; jj < 4; ++jj) part += (float)mv[c][4 + jj] * av1[jj];
    }
    part += __shfl_xor(part, 1);
    part += __shfl_xor(part, 2);

    if (MODE == 0) {
        float att = fsigmoid(part + abias[0]);
        float scale = att * em_l[el];
        bf16* edst = efout + (size_t)(ebase + el) * H + q * 32;
#pragma unroll
        for (int c = 0; c < 4; ++c) {
            bf16x8 o;
#pragma unroll
            for (int jj = 0; jj < 8; ++jj) o[jj] = (bf16)((float)mv[c][jj] * scale);
            *(bf16x8*)(edst + c * 8) = o;
        }
    } else {
        if (q == 0) {
            int rr = row_l[el], cc = col_l[el];
            float dx = xg[rr * 3 + 0] - xg[cc * 3 + 0];
            float dy = xg[rr * 3 + 1] - xg[cc * 3 + 1];
            float dz = xg[rr * 3 + 2] - xg[cc * 3 + 2];
            float radial = dx * dx + dy * dy + dz * dz;
            float inv = 1.f / (sqrtf(radial + 1e-8f) + 1.f);
            float s = part * em_l[el] * inv;
            int sI = ebase + el;
            trans[sI * 3 + 0] = dx * s;
            trans[sI * 3 + 1] = dy * s;
            trans[sI * 3 + 2] = dz * s;
        }
    }
}

// ---------------- node MLP kernel ----------------
__global__ __launch_bounds__(256, 2) void node_kernel(
    float* __restrict__ h_cur, bf16* __restrict__ h_bf, const bf16* __restrict__ agg_bf,
    const bf16* __restrict__ w1t, const float* __restrict__ b1,
    const bf16* __restrict__ w2t, const float* __restrict__ b2,
    const float* __restrict__ nmask) {
    constexpr int SRN = 264;
    constexpr int TRN = 136;
    __shared__ __align__(16) bf16 ninp[64 * SRN];
    __shared__ __align__(16) bf16 t1[64 * TRN];

    int t = threadIdx.x, lane = t & 63, wv = t >> 6;
    int lr = lane & 15, lg = lane >> 4;
    int nbase = blockIdx.x * 64;

    {   // stage ninp = [bf16(h), agg_bf]
        int nl = t >> 2, q = t & 3;
        int node = nbase + nl;
        bf16* dst = ninp + nl * SRN;
        if (node < N_NODES) {
            const float4* hr = (const float4*)(h_cur + (size_t)node * H);
            const bf16* ar = agg_bf + (size_t)node * H;
#pragma unroll
            for (int pp = 0; pp < 8; ++pp) {
                int ch = pp * 4 + q;
                float4 v = hr[ch];
                dst[ch * 4 + 0] = (bf16)v.x; dst[ch * 4 + 1] = (bf16)v.y;
                dst[ch * 4 + 2] = (bf16)v.z; dst[ch * 4 + 3] = (bf16)v.w;
            }
#pragma unroll
            for (int pp = 0; pp < 4; ++pp) {
                int ch = pp * 4 + q;
                *(bf16x8*)(dst + 128 + ch * 8) = *(const bf16x8*)(ar + ch * 8);
            }
        } else {
#pragma unroll
            for (int pp = 0; pp < 8; ++pp) {
                int ch = pp * 4 + q;
#pragma unroll
                for (int k = 0; k < 4; ++k) {
                    dst[ch * 4 + k] = (bf16)0.f;
                    dst[128 + ch * 4 + k] = (bf16)0.f;
                }
            }
        }
    }
    __syncthreads();

    f32x4 acc[4][2];
#pragma unroll
    for (int er = 0; er < 4; ++er)
#pragma unroll
        for (int j = 0; j < 2; ++j) acc[er][j] = (f32x4)0.f;
    wave_gemm<8, SRN, 256>(ninp, w1t, acc, lr, lg, wv);
    epi_silu_store(acc, b1, t1, TRN, lr, lg, wv);
    __syncthreads();

    f32x4 acc2[4][2];
#pragma unroll
    for (int er = 0; er < 4; ++er)
#pragma unroll
        for (int j = 0; j < 2; ++j) acc2[er][j] = (f32x4)0.f;
    wave_gemm<4, TRN, 128>(t1, w2t, acc2, lr, lg, wv);

    float bb0 = b2[(wv * 2 + 0) * 16 + lr];
    float bb1 = b2[(wv * 2 + 1) * 16 + lr];
#pragma unroll
    for (int er = 0; er < 4; ++er) {
#pragma unroll
        for (int j = 0; j < 2; ++j) {
            float bb = j ? bb1 : bb0;
            int feat = (wv * 2 + j) * 16 + lr;
#pragma unroll
            for (int r = 0; r < 4; ++r) {
                int node = nbase + er * 16 + lg * 4 + r;
                if (node < N_NODES) {
                    size_t idx = (size_t)node * H + feat;
                    float nm = nmask[node];
                    float v = (h_cur[idx] + acc2[er][j][r] + bb) * nm;  // fp32 residual
                    h_cur[idx] = v;
                    h_bf[idx] = (bf16)v;
                }
            }
        }
    }
}

// ---------------- launch ----------------
extern "C" void kernel_launch(void* const* d_in, const int* in_sizes, int n_in,
                              void* d_out, int out_size, void* d_ws, size_t ws_size,
                              hipStream_t stream) {
    (void)in_sizes; (void)n_in; (void)out_size; (void)ws_size;
    const float* h_in  = (const float*)d_in[0];
    const float* x_in  = (const float*)d_in[1];
    const int*   ei    = (const int*)d_in[2];
    const float* eattr = (const float*)d_in[3];
    const float* nmask = (const float*)d_in[4];
    const float* emask = (const float*)d_in[5];
    const float* e_w1  = (const float*)d_in[6];
    const float* e_b1  = (const float*)d_in[7];
    const float* e_w2  = (const float*)d_in[8];
    const float* e_b2  = (const float*)d_in[9];
    const float* a_w   = (const float*)d_in[10];
    const float* a_b   = (const float*)d_in[11];
    const float* n_w1  = (const float*)d_in[12];
    const float* n_b1  = (const float*)d_in[13];
    const float* n_w2  = (const float*)d_in[14];
    const float* n_b2  = (const float*)d_in[15];
    const float* c_w1  = (const float*)d_in[16];
    const float* c_b1  = (const float*)d_in[17];
    const float* c_w2  = (const float*)d_in[18];
    const float* c_b2  = (const float*)d_in[19];
    const float* c_w3  = (const float*)d_in[20];
    float* out = (float*)d_out;

    char* p = (char*)d_ws;
    auto alloc = [&](size_t bytes) { char* r = p; p += (bytes + 255) & ~(size_t)255; return r; };
    float* h_cur  = (float*)alloc((size_t)N_NODES * H * 4);
    bf16*  h_bf   = (bf16*) alloc((size_t)N_NODES * H * 2);
    bf16*  agg_bf = (bf16*) alloc((size_t)N_NODES * H * 2);
    bf16*  ea_bf  = (bf16*) alloc((size_t)N_EDGES * 2 * 2);
    bf16*  ef     = (bf16*) alloc((size_t)N_EDGES * H * 2);   // 204.8 MB, slot-indexed
    float* trans  = (float*)ef;                               // alias: ef dead before edge<1>
    int*   deg    = (int*)  alloc((size_t)N_NODES * 4);
    int*   off    = (int*)  alloc((size_t)N_NODES * 4);
    int*   cursor = (int*)  alloc((size_t)N_NODES * 4);
    int*   bsum   = (int*)  alloc((size_t)NB_SCAN * 4);
    int*   eids   = (int*)  alloc((size_t)N_EDGES * 4);
    bf16*  e_w1t  = (bf16*) alloc((size_t)2 * 128 * 288 * 2);
    bf16*  e_w2t  = (bf16*) alloc((size_t)2 * 128 * 128 * 2);
    bf16*  n_w1t  = (bf16*) alloc((size_t)2 * 128 * 256 * 2);
    bf16*  n_w2t  = (bf16*) alloc((size_t)2 * 128 * 128 * 2);
    bf16*  c_w1t  = (bf16*) alloc((size_t)128 * 288 * 2);
    bf16*  c_w2t  = (bf16*) alloc((size_t)128 * 128 * 2);

    auto tp = [&](bf16* dst, const float* src, int K, int KP) {
        int tot = 128 * KP;
        transpose_pad_kernel<<<(tot + 255) / 256, 256, 0, stream>>>(dst, src, K, 128, KP);
    };
    tp(e_w1t, e_w1, 258, 288);               tp(e_w1t + 128 * 288, e_w1 + 258 * 128, 258, 288);
    tp(e_w2t, e_w2, 128, 128);               tp(e_w2t + 128 * 128, e_w2 + 128 * 128, 128, 128);
    tp(n_w1t, n_w1, 256, 256);               tp(n_w1t + 128 * 256, n_w1 + 256 * 128, 256, 256);
    tp(n_w2t, n_w2, 128, 128);               tp(n_w2t + 128 * 128, n_w2 + 128 * 128, 128, 128);
    tp(c_w1t, c_w1, 258, 288);
    tp(c_w2t, c_w2, 128, 128);

    h_init_kernel<<<(N_NODES * H + 255) / 256, 256, 0, stream>>>(h_in, h_cur, h_bf, N_NODES * H);
    ea_kernel<<<(N_EDGES + 255) / 256, 256, 0, stream>>>(x_in, ei, eattr, ea_bf);

    // ---- CSR build ----
    hipMemsetAsync(deg, 0, (size_t)N_NODES * 4, stream);
    count_kernel<<<(N_EDGES + 255) / 256, 256, 0, stream>>>(ei, deg);
    scan1_kernel<<<NB_SCAN, 256, 0, stream>>>(deg, off, bsum);
    scan2_kernel<<<1, 256, 0, stream>>>(bsum);
    scan3_kernel<<<NB_SCAN, 256, 0, stream>>>(off, cursor, bsum);
    fill_kernel<<<(N_EDGES + 255) / 256, 256, 0, stream>>>(ei, cursor, eids);

    int ngrid = (N_NODES + 3) / 4;
    for (int i = 0; i < 2; ++i) {
        edge_kernel<0><<<N_EDGES / 64, 256, 0, stream>>>(
            h_bf, ea_bf, ei, emask, eids,
            e_w1t + (size_t)i * 128 * 288, e_b1 + i * H,
            e_w2t + (size_t)i * 128 * 128, e_b2 + i * H,
            a_w + i * H, a_b + i, nullptr, ef, nullptr);
        gather_h_kernel<<<ngrid, 256, 0, stream>>>(ef, off, deg, agg_bf);
        node_kernel<<<(N_NODES + 63) / 64, 256, 0, stream>>>(
            h_cur, h_bf, agg_bf,
            n_w1t + (size_t)i * 128 * 256, n_b1 + i * H,
            n_w2t + (size_t)i * 128 * 128, n_b2 + i * H, nmask);
    }
    edge_kernel<1><<<N_EDGES / 64, 256, 0, stream>>>(
        h_bf, ea_bf, ei, emask, eids,
        c_w1t, c_b1, c_w2t, c_b2, c_w3, nullptr, x_in, nullptr, trans);
    gather_x_kernel<<<ngrid, 256, 0, stream>>>(trans, off, deg, x_in, nmask,
                                               out + (size_t)N_NODES * H);

    out_h_kernel<<<(N_NODES * H + 255) / 256, 256, 0, stream>>>(h_cur, nmask, out);
}

// Round 10
// 906.567 us; speedup vs baseline: 1.5931x; 1.0559x over previous
//
#include <hip/hip_runtime.h>
#include <hip/hip_bf16.h>
#include <math.h>
#include <string.h>

#define DEV __device__ __forceinline__

typedef __bf16 bf16;
typedef bf16 bf16x8 __attribute__((ext_vector_type(8)));
typedef bf16 bf16x2 __attribute__((ext_vector_type(2)));
typedef float f32x4 __attribute__((ext_vector_type(4)));
typedef unsigned int uint;

constexpr int N_NODES = 50000;
constexpr int N_EDGES = 800000;
constexpr int H = 128;
constexpr int NB_SCAN = (N_NODES + 255) / 256;  // 196

DEV float fsilu(float x) { return x / (1.f + __expf(-x)); }
DEV float fsigmoid(float x) { return 1.f / (1.f + __expf(-x)); }

// ---------------- small prep kernels ----------------

__global__ void transpose_pad_kernel(bf16* __restrict__ dst, const float* __restrict__ src,
                                     int K, int Nf, int KP) {
    int idx = blockIdx.x * 256 + threadIdx.x;
    if (idx >= Nf * KP) return;
    int n = idx / KP, k = idx - n * KP;
    dst[idx] = (k < K) ? (bf16)src[k * Nf + n] : (bf16)0.f;
}

__global__ void h_init_kernel(const float* __restrict__ h, float* __restrict__ h_cur,
                              bf16* __restrict__ h_bf, int n) {
    int i = blockIdx.x * 256 + threadIdx.x;
    if (i < n) { float v = h[i]; h_cur[i] = v; h_bf[i] = (bf16)v; }
}

__global__ void out_h_kernel(const float* __restrict__ h_cur, const float* __restrict__ nmask,
                             float* __restrict__ out) {
    int i = blockIdx.x * 256 + threadIdx.x;
    if (i < N_NODES * H) out[i] = h_cur[i] * nmask[i >> 7];
}

// ---------------- CSR build (group edges by row) ----------------

__global__ void count_kernel(const int* __restrict__ ei, int* __restrict__ deg) {
    int e = blockIdx.x * 256 + threadIdx.x;
    if (e < N_EDGES) atomicAdd(&deg[ei[e]], 1);
}

__global__ void scan1_kernel(const int* __restrict__ deg, int* __restrict__ off,
                             int* __restrict__ bsum) {
    __shared__ int s[256];
    int t = threadIdx.x, i = blockIdx.x * 256 + t;
    int v = (i < N_NODES) ? deg[i] : 0;
    s[t] = v;
    __syncthreads();
#pragma unroll
    for (int st = 1; st < 256; st <<= 1) {
        int x = (t >= st) ? s[t - st] : 0;
        __syncthreads();
        s[t] += x;
        __syncthreads();
    }
    if (i < N_NODES) off[i] = s[t] - v;
    if (t == 255) bsum[blockIdx.x] = s[255];
}

__global__ void scan2_kernel(int* __restrict__ bsum) {
    __shared__ int s[256];
    int t = threadIdx.x;
    int v = (t < NB_SCAN) ? bsum[t] : 0;
    s[t] = v;
    __syncthreads();
#pragma unroll
    for (int st = 1; st < 256; st <<= 1) {
        int x = (t >= st) ? s[t - st] : 0;
        __syncthreads();
        s[t] += x;
        __syncthreads();
    }
    if (t < NB_SCAN) bsum[t] = s[t] - v;
}

__global__ void scan3_kernel(int* __restrict__ off, int* __restrict__ cursor,
                             const int* __restrict__ bsum) {
    int i = blockIdx.x * 256 + threadIdx.x;
    if (i >= N_NODES) return;
    int o = off[i] + bsum[blockIdx.x];
    off[i] = o;
    cursor[i] = o;
}

// assign slots and write SLOT-ORDERED packed metadata:
// rc_pm[slot] = row<<16 | col (N<65536), ea_pm[slot] = {radial, eattr} bf16,
// em_pm[slot] = emask bf16. No eids array needed downstream.
__global__ void fill2_kernel(const int* __restrict__ ei, const float* __restrict__ x,
                             const float* __restrict__ eattr, const float* __restrict__ emask,
                             int* __restrict__ cursor, uint* __restrict__ rc_pm,
                             bf16* __restrict__ ea_pm, bf16* __restrict__ em_pm) {
    int e = blockIdx.x * 256 + threadIdx.x;
    if (e >= N_EDGES) return;
    int r = ei[e], c = ei[N_EDGES + e];
    int slot = atomicAdd(&cursor[r], 1);
    rc_pm[slot] = ((uint)r << 16) | (uint)c;
    float dx = x[r * 3 + 0] - x[c * 3 + 0];
    float dy = x[r * 3 + 1] - x[c * 3 + 1];
    float dz = x[r * 3 + 2] - x[c * 3 + 2];
    float radial = dx * dx + dy * dy + dz * dz;
    ea_pm[(size_t)slot * 2 + 0] = (bf16)radial;
    ea_pm[(size_t)slot * 2 + 1] = (bf16)eattr[e];
    em_pm[slot] = (bf16)emask[e];
}

// ---------------- gathers (CSR-contiguous) ----------------

__global__ __launch_bounds__(256) void gather_h_kernel(
    const bf16* __restrict__ ef, const int* __restrict__ off, const int* __restrict__ deg,
    bf16* __restrict__ agg_bf) {
    int t = threadIdx.x, lane = t & 63, wv = t >> 6;
    int n = blockIdx.x * 4 + wv;
    if (n >= N_NODES) return;
    int st = off[n], dg = deg[n];
    const bf16* bp = ef + (size_t)st * H + lane * 2;
    float s0 = 0.f, s1 = 0.f;
    for (int k = 0; k < dg; ++k) {
        uint v = *(const uint*)(bp + (size_t)k * H);
        s0 += __uint_as_float(v << 16);
        s1 += __uint_as_float(v & 0xffff0000u);
    }
    bf16x2 o;
    o[0] = (bf16)(s0 * 0.01f);
    o[1] = (bf16)(s1 * 0.01f);
    *(bf16x2*)(agg_bf + (size_t)n * H + lane * 2) = o;
}

__global__ __launch_bounds__(256) void gather_x_kernel(
    const float* __restrict__ trans, const int* __restrict__ off, const int* __restrict__ deg,
    const float* __restrict__ x, const float* __restrict__ nmask, float* __restrict__ outx) {
    int t = threadIdx.x, lane = t & 63, wv = t >> 6;
    int n = blockIdx.x * 4 + wv;
    if (n >= N_NODES) return;
    int st = off[n], dg = deg[n];
    float sx = 0.f, sy = 0.f, sz = 0.f;
    for (int k = lane; k < dg; k += 64) {
        const float* tp = trans + (size_t)(st + k) * 3;
        sx += tp[0];
        sy += tp[1];
        sz += tp[2];
    }
#pragma unroll
    for (int m = 1; m < 64; m <<= 1) {
        sx += __shfl_xor(sx, m);
        sy += __shfl_xor(sy, m);
        sz += __shfl_xor(sz, m);
    }
    if (lane == 0) {
        float nm = nmask[n];
        outx[n * 3 + 0] = (x[n * 3 + 0] + sx * 0.01f) * nm;
        outx[n * 3 + 1] = (x[n * 3 + 1] + sy * 0.01f) * nm;
        outx[n * 3 + 2] = (x[n * 3 + 2] + sz * 0.01f) * nm;
    }
}

// ---------------- MFMA helpers ----------------
// A layout (16x16x32 bf16): lane holds A[lane&15][(lane>>4)*8 + i]
// C/D layout (HW-verified): col = lane&15, row = (lane>>4)*4 + reg

template <int KCHUNKS, int ASTRIDE, int BSTRIDE>
DEV void wave_gemm(const bf16* A_lds, const bf16* __restrict__ Bt,
                   f32x4 (&acc)[4][2], int lr, int lg, int wv) {
#pragma unroll
    for (int kk = 0; kk < KCHUNKS; ++kk) {
        int ko = kk * 32 + lg * 8;
        bf16x8 a[4], b[2];
#pragma unroll
        for (int er = 0; er < 4; ++er)
            a[er] = *(const bf16x8*)(A_lds + (er * 16 + lr) * ASTRIDE + ko);
#pragma unroll
        for (int j = 0; j < 2; ++j)
            b[j] = *(const bf16x8*)(Bt + (size_t)((wv * 2 + j) * 16 + lr) * BSTRIDE + ko);
#pragma unroll
        for (int er = 0; er < 4; ++er)
#pragma unroll
            for (int j = 0; j < 2; ++j)
                acc[er][j] = __builtin_amdgcn_mfma_f32_16x16x32_bf16(a[er], b[j], acc[er][j], 0, 0, 0);
    }
}

DEV void epi_silu_store(const f32x4 (&acc)[4][2], const float* __restrict__ bias,
                        bf16* out_lds, int OSTRIDE, int lr, int lg, int wv) {
    float b0 = bias[(wv * 2 + 0) * 16 + lr];
    float b1 = bias[(wv * 2 + 1) * 16 + lr];
#pragma unroll
    for (int er = 0; er < 4; ++er) {
#pragma unroll
        for (int j = 0; j < 2; ++j) {
            float bb = j ? b1 : b0;
            int fcol = (wv * 2 + j) * 16 + lr;
#pragma unroll
            for (int r = 0; r < 4; ++r) {
                int rrow = er * 16 + lg * 4 + r;
                out_lds[rrow * OSTRIDE + fcol] = (bf16)fsilu(acc[er][j][r] + bb);
            }
        }
    }
}

// swizzled variant: [64][128] with 16B-slot XOR (slot ^= row&7)
DEV void epi_silu_store_swz(const f32x4 (&acc)[4][2], const float* __restrict__ bias,
                            bf16* out_lds, int lr, int lg, int wv) {
    float b0 = bias[(wv * 2 + 0) * 16 + lr];
    float b1 = bias[(wv * 2 + 1) * 16 + lr];
#pragma unroll
    for (int er = 0; er < 4; ++er) {
#pragma unroll
        for (int j = 0; j < 2; ++j) {
            float bb = j ? b1 : b0;
            int fcol = (wv * 2 + j) * 16 + lr;
#pragma unroll
            for (int r = 0; r < 4; ++r) {
                int rrow = er * 16 + lg * 4 + r;
                int sl = (fcol >> 3) ^ (rrow & 7);
                out_lds[rrow * 128 + sl * 8 + (fcol & 7)] = (bf16)fsilu(acc[er][j][r] + bb);
            }
        }
    }
}

// ---------------- edge / coord kernel (slot-ordered, coalesced metadata) ----------------
// Block handles 64 consecutive CSR slots. All metadata (rc_pm packed row/col,
// ea_pm, em_pm) is slot-ordered -> coalesced loads, no indirection chain.
// Staging: async global_load_lds into AR/AC [64][128], XOR slot swizzle on the
// GLOBAL source. LDS reuse: AR -> t1, AC -> mij. ~33.3 KB -> 4 blocks/CU.
// MODE 0: -> ef[slot][128] bf16. MODE 1: -> trans[slot][3] f32.
template <int MODE>
__global__ __launch_bounds__(256, 4) void edge_kernel(
    const bf16* __restrict__ h_bf, const bf16* __restrict__ ea_pm,
    const uint* __restrict__ rc_pm, const bf16* __restrict__ em_pm,
    const bf16* __restrict__ w1t, const float* __restrict__ b1,
    const bf16* __restrict__ w2t, const float* __restrict__ b2,
    const float* __restrict__ avec, const float* __restrict__ abias,
    const float* __restrict__ xg, bf16* __restrict__ efout, float* __restrict__ trans) {
    __shared__ __align__(16) bf16 AR[64 * 128];   // h[row] tile -> reused as t1 (swz)
    __shared__ __align__(16) bf16 AC[64 * 128];   // h[col] tile -> reused as mij (swz)
    __shared__ __align__(16) float avec_l[128];
    __shared__ int row_l[64];
    __shared__ int col_l[64];
    __shared__ float em_l[64];

    int t = threadIdx.x, lane = t & 63, wv = t >> 6;
    int lr = lane & 15, lg = lane >> 4;
    int ebase = blockIdx.x * 64;

    {   // async stage: each instr writes 4 rows x 256B = 1024B linear LDS
        int rsub = lane >> 4;     // row within 4-row group
        int slot = lane & 15;     // 16B slot within row
#pragma unroll
        for (int u = 0; u < 4; ++u) {
            int r = wv * 16 + u * 4 + rsub;
            uint rc = rc_pm[ebase + r];
            int nr = (int)(rc >> 16);
            int nc = (int)(rc & 0xffffu);
            int sl = slot ^ (r & 7);   // pre-swizzled source
            const bf16* gpr = h_bf + (size_t)nr * H + sl * 8;
            __builtin_amdgcn_global_load_lds(
                (const __attribute__((address_space(1))) void*)gpr,
                (__attribute__((address_space(3))) void*)&AR[(wv * 16 + u * 4) * 128],
                16, 0, 0);
            const bf16* gpc = h_bf + (size_t)nc * H + sl * 8;
            __builtin_amdgcn_global_load_lds(
                (const __attribute__((address_space(1))) void*)gpc,
                (__attribute__((address_space(3))) void*)&AC[(wv * 16 + u * 4) * 128],
                16, 0, 0);
        }
    }
    if (t < 64) {
        uint rc = rc_pm[ebase + t];
        row_l[t] = (int)(rc >> 16);
        col_l[t] = (int)(rc & 0xffffu);
        em_l[t] = (float)em_pm[ebase + t];
    } else if (t < 192) {
        avec_l[t - 64] = avec[t - 64];
    }

    // ea K-tail in registers (coalesced slot-ordered read)
    uint eau[4];
#pragma unroll
    for (int er = 0; er < 4; ++er)
        eau[er] = *(const uint*)(ea_pm + (size_t)(ebase + er * 16 + lr) * 2);

    const bf16* bp0 = w1t + (size_t)((wv * 2 + 0) * 16 + lr) * 288 + lg * 8;
    const bf16* bp1 = w1t + (size_t)((wv * 2 + 1) * 16 + lr) * 288 + lg * 8;

    // preload B fragments kk=0..4 as uint4 (kept live past the barrier via asm)
    uint4 bv0[5], bv1[5];
#pragma unroll
    for (int kk = 0; kk < 5; ++kk) {
        bv0[kk] = *(const uint4*)(bp0 + kk * 32);
        bv1[kk] = *(const uint4*)(bp1 + kk * 32);
    }
#pragma unroll
    for (int kk = 0; kk < 5; ++kk) {
        asm volatile("" ::"v"(bv0[kk].x), "v"(bv0[kk].y), "v"(bv0[kk].z), "v"(bv0[kk].w));
        asm volatile("" ::"v"(bv1[kk].x), "v"(bv1[kk].y), "v"(bv1[kk].z), "v"(bv1[kk].w));
    }

    __syncthreads();  // drains global_load_lds (vmcnt) + meta stores

    f32x4 acc[4][2];
#pragma unroll
    for (int er = 0; er < 4; ++er)
#pragma unroll
        for (int j = 0; j < 2; ++j) acc[er][j] = (f32x4)0.f;

    // kk 0..3: h[row] from AR; kk 4..7: h[col] from AC (swizzled reads)
#pragma unroll
    for (int kk = 0; kk < 8; ++kk) {
        const bf16* Ab = (kk < 4) ? AR : AC;
        int k4 = kk & 3;
        bf16x8 a[4], b[2];
        b[0] = (kk < 5) ? __builtin_bit_cast(bf16x8, bv0[kk]) : *(const bf16x8*)(bp0 + kk * 32);
        b[1] = (kk < 5) ? __builtin_bit_cast(bf16x8, bv1[kk]) : *(const bf16x8*)(bp1 + kk * 32);
#pragma unroll
        for (int er = 0; er < 4; ++er) {
            int sl = (k4 * 4 + lg) ^ (lr & 7);
            a[er] = *(const bf16x8*)(Ab + (er * 16 + lr) * 128 + sl * 8);
        }
#pragma unroll
        for (int er = 0; er < 4; ++er)
#pragma unroll
            for (int j = 0; j < 2; ++j)
                acc[er][j] = __builtin_amdgcn_mfma_f32_16x16x32_bf16(a[er], b[j], acc[er][j], 0, 0, 0);
    }
    {   // kk 8: [radial, edge_attr, 0...] fragment (nonzero only for lg==0)
        bf16x8 a[4], b[2];
        b[0] = *(const bf16x8*)(bp0 + 8 * 32);
        b[1] = *(const bf16x8*)(bp1 + 8 * 32);
#pragma unroll
        for (int er = 0; er < 4; ++er) {
            bf16x8 f = (bf16x8)(bf16)0.f;
            if (lg == 0) {
                bf16x2 ep;
                memcpy(&ep, &eau[er], 4);
                f[0] = ep[0];
                f[1] = ep[1];
            }
            a[er] = f;
        }
#pragma unroll
        for (int er = 0; er < 4; ++er)
#pragma unroll
            for (int j = 0; j < 2; ++j)
                acc[er][j] = __builtin_amdgcn_mfma_f32_16x16x32_bf16(a[er], b[j], acc[er][j], 0, 0, 0);
    }
    __syncthreads();  // all waves done reading AR (and AC) in GEMM1

    // t1 = silu(GEMM1) -> AR (swizzled [64][128])
    epi_silu_store_swz(acc, b1, AR, lr, lg, wv);
    __syncthreads();  // t1 ready

    // GEMM2: A = t1 (AR, swz), B = w2t
    f32x4 acc2[4][2];
#pragma unroll
    for (int er = 0; er < 4; ++er)
#pragma unroll
        for (int j = 0; j < 2; ++j) acc2[er][j] = (f32x4)0.f;
    {
        const bf16* cp0 = w2t + (size_t)((wv * 2 + 0) * 16 + lr) * 128 + lg * 8;
        const bf16* cp1 = w2t + (size_t)((wv * 2 + 1) * 16 + lr) * 128 + lg * 8;
#pragma unroll
        for (int kk = 0; kk < 4; ++kk) {
            bf16x8 a[4], b[2];
            b[0] = *(const bf16x8*)(cp0 + kk * 32);
            b[1] = *(const bf16x8*)(cp1 + kk * 32);
#pragma unroll
            for (int er = 0; er < 4; ++er) {
                int sl = (kk * 4 + lg) ^ (lr & 7);
                a[er] = *(const bf16x8*)(AR + (er * 16 + lr) * 128 + sl * 8);
            }
#pragma unroll
            for (int er = 0; er < 4; ++er)
#pragma unroll
                for (int j = 0; j < 2; ++j)
                    acc2[er][j] = __builtin_amdgcn_mfma_f32_16x16x32_bf16(a[er], b[j], acc2[er][j], 0, 0, 0);
        }
    }

    bf16* mij = AC;  // safe: all GEMM1 AC reads completed before the pre-epi1 barrier
    epi_silu_store_swz(acc2, b2, mij, lr, lg, wv);
    __syncthreads();

    // per-edge dot over 128 feats: 4 threads/edge, shfl reduce (swizzled mij reads)
    int el = t >> 2, q = t & 3;
    float part = 0.f;
    bf16x8 mv[4];
#pragma unroll
    for (int c = 0; c < 4; ++c) {
        int sl = (q * 4 + c) ^ (el & 7);
        mv[c] = *(const bf16x8*)(mij + el * 128 + sl * 8);
        f32x4 av0 = *(const f32x4*)(avec_l + q * 32 + c * 8);
        f32x4 av1 = *(const f32x4*)(avec_l + q * 32 + c * 8 + 4);
#pragma unroll
        for (int jj = 0; jj < 4; ++jj) part += (float)mv[c][jj] * av0[jj];
#pragma unroll
        for (int jj = 0; jj < 4; ++jj) part += (float)mv[c][4 + jj] * av1[jj];
    }
    part += __shfl_xor(part, 1);
    part += __shfl_xor(part, 2);

    if (MODE == 0) {
        float att = fsigmoid(part + abias[0]);
        float scale = att * em_l[el];
        bf16* edst = efout + (size_t)(ebase + el) * H + q * 32;
#pragma unroll
        for (int c = 0; c < 4; ++c) {
            bf16x8 o;
#pragma unroll
            for (int jj = 0; jj < 8; ++jj) o[jj] = (bf16)((float)mv[c][jj] * scale);
            *(bf16x8*)(edst + c * 8) = o;
        }
    } else {
        if (q == 0) {
            int rr = row_l[el], cc = col_l[el];
            float dx = xg[rr * 3 + 0] - xg[cc * 3 + 0];
            float dy = xg[rr * 3 + 1] - xg[cc * 3 + 1];
            float dz = xg[rr * 3 + 2] - xg[cc * 3 + 2];
            float radial = dx * dx + dy * dy + dz * dz;
            float inv = 1.f / (sqrtf(radial + 1e-8f) + 1.f);
            float s = part * em_l[el] * inv;
            int sI = ebase + el;
            trans[sI * 3 + 0] = dx * s;
            trans[sI * 3 + 1] = dy * s;
            trans[sI * 3 + 2] = dz * s;
        }
    }
}

// ---------------- node MLP kernel ----------------
__global__ __launch_bounds__(256, 2) void node_kernel(
    float* __restrict__ h_cur, bf16* __restrict__ h_bf, const bf16* __restrict__ agg_bf,
    const bf16* __restrict__ w1t, const float* __restrict__ b1,
    const bf16* __restrict__ w2t, const float* __restrict__ b2,
    const float* __restrict__ nmask) {
    constexpr int SRN = 264;
    constexpr int TRN = 136;
    __shared__ __align__(16) bf16 ninp[64 * SRN];
    __shared__ __align__(16) bf16 t1[64 * TRN];

    int t = threadIdx.x, lane = t & 63, wv = t >> 6;
    int lr = lane & 15, lg = lane >> 4;
    int nbase = blockIdx.x * 64;

    {   // stage ninp = [bf16(h), agg_bf]
        int nl = t >> 2, q = t & 3;
        int node = nbase + nl;
        bf16* dst = ninp + nl * SRN;
        if (node < N_NODES) {
            const float4* hr = (const float4*)(h_cur + (size_t)node * H);
            const bf16* ar = agg_bf + (size_t)node * H;
#pragma unroll
            for (int pp = 0; pp < 8; ++pp) {
                int ch = pp * 4 + q;
                float4 v = hr[ch];
                dst[ch * 4 + 0] = (bf16)v.x; dst[ch * 4 + 1] = (bf16)v.y;
                dst[ch * 4 + 2] = (bf16)v.z; dst[ch * 4 + 3] = (bf16)v.w;
            }
#pragma unroll
            for (int pp = 0; pp < 4; ++pp) {
                int ch = pp * 4 + q;
                *(bf16x8*)(dst + 128 + ch * 8) = *(const bf16x8*)(ar + ch * 8);
            }
        } else {
#pragma unroll
            for (int pp = 0; pp < 8; ++pp) {
                int ch = pp * 4 + q;
#pragma unroll
                for (int k = 0; k < 4; ++k) {
                    dst[ch * 4 + k] = (bf16)0.f;
                    dst[128 + ch * 4 + k] = (bf16)0.f;
                }
            }
        }
    }
    __syncthreads();

    f32x4 acc[4][2];
#pragma unroll
    for (int er = 0; er < 4; ++er)
#pragma unroll
        for (int j = 0; j < 2; ++j) acc[er][j] = (f32x4)0.f;
    wave_gemm<8, SRN, 256>(ninp, w1t, acc, lr, lg, wv);
    epi_silu_store(acc, b1, t1, TRN, lr, lg, wv);
    __syncthreads();

    f32x4 acc2[4][2];
#pragma unroll
    for (int er = 0; er < 4; ++er)
#pragma unroll
        for (int j = 0; j < 2; ++j) acc2[er][j] = (f32x4)0.f;
    wave_gemm<4, TRN, 128>(t1, w2t, acc2, lr, lg, wv);

    float bb0 = b2[(wv * 2 + 0) * 16 + lr];
    float bb1 = b2[(wv * 2 + 1) * 16 + lr];
#pragma unroll
    for (int er = 0; er < 4; ++er) {
#pragma unroll
        for (int j = 0; j < 2; ++j) {
            float bb = j ? bb1 : bb0;
            int feat = (wv * 2 + j) * 16 + lr;
#pragma unroll
            for (int r = 0; r < 4; ++r) {
                int node = nbase + er * 16 + lg * 4 + r;
                if (node < N_NODES) {
                    size_t idx = (size_t)node * H + feat;
                    float nm = nmask[node];
                    float v = (h_cur[idx] + acc2[er][j][r] + bb) * nm;  // fp32 residual
                    h_cur[idx] = v;
                    h_bf[idx] = (bf16)v;
                }
            }
        }
    }
}

// ---------------- launch ----------------
extern "C" void kernel_launch(void* const* d_in, const int* in_sizes, int n_in,
                              void* d_out, int out_size, void* d_ws, size_t ws_size,
                              hipStream_t stream) {
    (void)in_sizes; (void)n_in; (void)out_size; (void)ws_size;
    const float* h_in  = (const float*)d_in[0];
    const float* x_in  = (const float*)d_in[1];
    const int*   ei    = (const int*)d_in[2];
    const float* eattr = (const float*)d_in[3];
    const float* nmask = (const float*)d_in[4];
    const float* emask = (const float*)d_in[5];
    const float* e_w1  = (const float*)d_in[6];
    const float* e_b1  = (const float*)d_in[7];
    const float* e_w2  = (const float*)d_in[8];
    const float* e_b2  = (const float*)d_in[9];
    const float* a_w   = (const float*)d_in[10];
    const float* a_b   = (const float*)d_in[11];
    const float* n_w1  = (const float*)d_in[12];
    const float* n_b1  = (const float*)d_in[13];
    const float* n_w2  = (const float*)d_in[14];
    const float* n_b2  = (const float*)d_in[15];
    const float* c_w1  = (const float*)d_in[16];
    const float* c_b1  = (const float*)d_in[17];
    const float* c_w2  = (const float*)d_in[18];
    const float* c_b2  = (const float*)d_in[19];
    const float* c_w3  = (const float*)d_in[20];
    float* out = (float*)d_out;

    char* p = (char*)d_ws;
    auto alloc = [&](size_t bytes) { char* r = p; p += (bytes + 255) & ~(size_t)255; return r; };
    float* h_cur  = (float*)alloc((size_t)N_NODES * H * 4);
    bf16*  h_bf   = (bf16*) alloc((size_t)N_NODES * H * 2);
    bf16*  agg_bf = (bf16*) alloc((size_t)N_NODES * H * 2);
    bf16*  ea_pm  = (bf16*) alloc((size_t)N_EDGES * 2 * 2);   // slot-ordered {radial, eattr}
    bf16*  ef     = (bf16*) alloc((size_t)N_EDGES * H * 2);   // 204.8 MB, slot-indexed
    float* trans  = (float*)ef;                               // alias: ef dead before edge<1>
    int*   deg    = (int*)  alloc((size_t)N_NODES * 4);
    int*   off    = (int*)  alloc((size_t)N_NODES * 4);
    int*   cursor = (int*)  alloc((size_t)N_NODES * 4);
    int*   bsum   = (int*)  alloc((size_t)NB_SCAN * 4);
    uint*  rc_pm  = (uint*) alloc((size_t)N_EDGES * 4);       // slot-ordered row<<16|col
    bf16*  em_pm  = (bf16*) alloc((size_t)N_EDGES * 2);       // slot-ordered emask (+1.6MB)
    bf16*  e_w1t  = (bf16*) alloc((size_t)2 * 128 * 288 * 2);
    bf16*  e_w2t  = (bf16*) alloc((size_t)2 * 128 * 128 * 2);
    bf16*  n_w1t  = (bf16*) alloc((size_t)2 * 128 * 256 * 2);
    bf16*  n_w2t  = (bf16*) alloc((size_t)2 * 128 * 128 * 2);
    bf16*  c_w1t  = (bf16*) alloc((size_t)128 * 288 * 2);
    bf16*  c_w2t  = (bf16*) alloc((size_t)128 * 128 * 2);

    auto tp = [&](bf16* dst, const float* src, int K, int KP) {
        int tot = 128 * KP;
        transpose_pad_kernel<<<(tot + 255) / 256, 256, 0, stream>>>(dst, src, K, 128, KP);
    };
    tp(e_w1t, e_w1, 258, 288);               tp(e_w1t + 128 * 288, e_w1 + 258 * 128, 258, 288);
    tp(e_w2t, e_w2, 128, 128);               tp(e_w2t + 128 * 128, e_w2 + 128 * 128, 128, 128);
    tp(n_w1t, n_w1, 256, 256);               tp(n_w1t + 128 * 256, n_w1 + 256 * 128, 256, 256);
    tp(n_w2t, n_w2, 128, 128);               tp(n_w2t + 128 * 128, n_w2 + 128 * 128, 128, 128);
    tp(c_w1t, c_w1, 258, 288);
    tp(c_w2t, c_w2, 128, 128);

    h_init_kernel<<<(N_NODES * H + 255) / 256, 256, 0, stream>>>(h_in, h_cur, h_bf, N_NODES * H);

    // ---- CSR build + slot-ordered packed metadata ----
    hipMemsetAsync(deg, 0, (size_t)N_NODES * 4, stream);
    count_kernel<<<(N_EDGES + 255) / 256, 256, 0, stream>>>(ei, deg);
    scan1_kernel<<<NB_SCAN, 256, 0, stream>>>(deg, off, bsum);
    scan2_kernel<<<1, 256, 0, stream>>>(bsum);
    scan3_kernel<<<NB_SCAN, 256, 0, stream>>>(off, cursor, bsum);
    fill2_kernel<<<(N_EDGES + 255) / 256, 256, 0, stream>>>(
        ei, x_in, eattr, emask, cursor, rc_pm, ea_pm, em_pm);

    int ngrid = (N_NODES + 3) / 4;
    for (int i = 0; i < 2; ++i) {
        edge_kernel<0><<<N_EDGES / 64, 256, 0, stream>>>(
            h_bf, ea_pm, rc_pm, em_pm,
            e_w1t + (size_t)i * 128 * 288, e_b1 + i * H,
            e_w2t + (size_t)i * 128 * 128, e_b2 + i * H,
            a_w + i * H, a_b + i, nullptr, ef, nullptr);
        gather_h_kernel<<<ngrid, 256, 0, stream>>>(ef, off, deg, agg_bf);
        node_kernel<<<(N_NODES + 63) / 64, 256, 0, stream>>>(
            h_cur, h_bf, agg_bf,
            n_w1t + (size_t)i * 128 * 256, n_b1 + i * H,
            n_w2t + (size_t)i * 128 * 128, n_b2 + i * H, nmask);
    }
    edge_kernel<1><<<N_EDGES / 64, 256, 0, stream>>>(
        h_bf, ea_pm, rc_pm, em_pm,
        c_w1t, c_b1, c_w2t, c_b2, c_w3, nullptr, x_in, nullptr, trans);
    gather_x_kernel<<<ngrid, 256, 0, stream>>>(trans, off, deg, x_in, nmask,
                                               out + (size_t)N_NODES * H);

    out_h_kernel<<<(N_NODES * H + 255) / 256, 256, 0, stream>>>(h_cur, nmask, out);
}